// Round 1
// baseline (11391.492 us; speedup 1.0000x reference)
//
#include <hip/hip_runtime.h>

#define N_NODES 50000
#define E_EDGES 800000
#define NFEAT   512
#define NHID    256
#define NCLS    100
#define LN_EPS  1e-5f

// ---------------------------------------------------------------------------
// GEMM: C[M,Nc] = op(A[M,K]) @ W[K,Nc] + bias   (op = identity or relu)
// 64x64 tile, BK=16, 256 threads, 4x4 micro-tile per thread. fp32.
// ---------------------------------------------------------------------------
template<int RELU_A>
__global__ __launch_bounds__(256)
void gemm_bias_kernel(const float* __restrict__ A, const float* __restrict__ W,
                      const float* __restrict__ bias, float* __restrict__ C,
                      int M, int K, int Nc)
{
    __shared__ float As[16][68];   // [k][m], padded
    __shared__ float Ws[16][68];   // [k][n], padded

    const int tid = threadIdx.x;
    const int bm  = blockIdx.x * 64;
    const int bn  = blockIdx.y * 64;
    const int tm  = (tid >> 4) << 2;   // 0..60
    const int tn  = (tid & 15) << 2;   // 0..60

    const int ar = tid >> 2;           // 0..63   A-tile row
    const int ak = (tid & 3) << 2;     // 0,4,8,12
    const int wk = tid >> 4;           // 0..15   W-tile k
    const int wn = (tid & 15) << 2;    // 0..60

    float acc[4][4] = {{0.f,0.f,0.f,0.f},{0.f,0.f,0.f,0.f},
                       {0.f,0.f,0.f,0.f},{0.f,0.f,0.f,0.f}};

    for (int k0 = 0; k0 < K; k0 += 16) {
        // ---- load A tile (64 rows x 16 k), one float4 per thread ----
        {
            const int row = bm + ar;
            float4 v = make_float4(0.f, 0.f, 0.f, 0.f);
            if (row < M) {
                v = *reinterpret_cast<const float4*>(&A[(size_t)row * K + k0 + ak]);
                if (RELU_A) {
                    v.x = fmaxf(v.x, 0.f); v.y = fmaxf(v.y, 0.f);
                    v.z = fmaxf(v.z, 0.f); v.w = fmaxf(v.w, 0.f);
                }
            }
            As[ak + 0][ar] = v.x; As[ak + 1][ar] = v.y;
            As[ak + 2][ar] = v.z; As[ak + 3][ar] = v.w;
        }
        // ---- load W tile (16 k x 64 n), one float4 per thread ----
        {
            const int col = bn + wn;
            float4 v = make_float4(0.f, 0.f, 0.f, 0.f);
            const float* wp = &W[(size_t)(k0 + wk) * Nc];
            if (col + 3 < Nc) {
                v = *reinterpret_cast<const float4*>(&wp[col]);
            } else if (col < Nc) {
                v.x = wp[col];
                if (col + 1 < Nc) v.y = wp[col + 1];
                if (col + 2 < Nc) v.z = wp[col + 2];
            }
            Ws[wk][wn + 0] = v.x; Ws[wk][wn + 1] = v.y;
            Ws[wk][wn + 2] = v.z; Ws[wk][wn + 3] = v.w;
        }
        __syncthreads();

        #pragma unroll
        for (int k = 0; k < 16; ++k) {
            const float a0 = As[k][tm + 0], a1 = As[k][tm + 1],
                        a2 = As[k][tm + 2], a3 = As[k][tm + 3];
            const float b0 = Ws[k][tn + 0], b1 = Ws[k][tn + 1],
                        b2 = Ws[k][tn + 2], b3 = Ws[k][tn + 3];
            acc[0][0] += a0 * b0; acc[0][1] += a0 * b1; acc[0][2] += a0 * b2; acc[0][3] += a0 * b3;
            acc[1][0] += a1 * b0; acc[1][1] += a1 * b1; acc[1][2] += a1 * b2; acc[1][3] += a1 * b3;
            acc[2][0] += a2 * b0; acc[2][1] += a2 * b1; acc[2][2] += a2 * b2; acc[2][3] += a2 * b3;
            acc[3][0] += a3 * b0; acc[3][1] += a3 * b1; acc[3][2] += a3 * b2; acc[3][3] += a3 * b3;
        }
        __syncthreads();
    }

    #pragma unroll
    for (int i = 0; i < 4; ++i) {
        const int row = bm + tm + i;
        if (row >= M) continue;
        #pragma unroll
        for (int j = 0; j < 4; ++j) {
            const int col = bn + tn + j;
            if (col < Nc)
                C[(size_t)row * Nc + col] = acc[i][j] + bias[col];
        }
    }
}

// ---------------------------------------------------------------------------
// SpMM scatter: out[rows[e], :] += vals[e] * feat[cols[e], :]   (F = 256)
// One wave per edge; each lane handles 4 consecutive floats (float4 gather,
// 4 fp32 global atomics).
// ---------------------------------------------------------------------------
__global__ __launch_bounds__(256)
void spmm_scatter_kernel(const int* __restrict__ rows, const int* __restrict__ cols,
                         const float* __restrict__ vals, const float* __restrict__ feat,
                         float* __restrict__ out, int E)
{
    const int gid  = blockIdx.x * 256 + threadIdx.x;
    const int e    = gid >> 6;
    const int lane = gid & 63;
    if (e >= E) return;

    const int   r = rows[e];
    const int   c = cols[e];
    const float v = vals[e];

    const float4 f = *reinterpret_cast<const float4*>(&feat[(size_t)c * NHID + lane * 4]);
    float* o = &out[(size_t)r * NHID + lane * 4];
    atomicAdd(o + 0, v * f.x);
    atomicAdd(o + 1, v * f.y);
    atomicAdd(o + 2, v * f.z);
    atomicAdd(o + 3, v * f.w);
}

// ---------------------------------------------------------------------------
// LayerNorm over concat([A,B], axis=1) (512 feats) + affine + ReLU -> C[N,512]
// One wave per row; lane l holds feats [8l, 8l+8).
// ---------------------------------------------------------------------------
__global__ __launch_bounds__(256)
void ln_concat_relu_kernel(const float* __restrict__ A, const float* __restrict__ B,
                           const float* __restrict__ g, const float* __restrict__ be,
                           float* __restrict__ C, int n)
{
    const int gid  = blockIdx.x * 256 + threadIdx.x;
    const int row  = gid >> 6;
    const int lane = gid & 63;
    if (row >= n) return;

    const float* src = (lane < 32) ? &A[(size_t)row * NHID + lane * 8]
                                   : &B[(size_t)row * NHID + (lane - 32) * 8];
    const float4 v0 = *reinterpret_cast<const float4*>(src);
    const float4 v1 = *reinterpret_cast<const float4*>(src + 4);
    float x[8] = {v0.x, v0.y, v0.z, v0.w, v1.x, v1.y, v1.z, v1.w};

    float s = 0.f;
    #pragma unroll
    for (int j = 0; j < 8; ++j) s += x[j];
    #pragma unroll
    for (int m = 1; m < 64; m <<= 1) s += __shfl_xor(s, m, 64);
    const float mean = s * (1.f / 512.f);

    float sq = 0.f;
    #pragma unroll
    for (int j = 0; j < 8; ++j) { const float d = x[j] - mean; sq += d * d; }
    #pragma unroll
    for (int m = 1; m < 64; m <<= 1) sq += __shfl_xor(sq, m, 64);
    const float rstd = rsqrtf(sq * (1.f / 512.f) + LN_EPS);

    const int fb = lane * 8;
    float o[8];
    #pragma unroll
    for (int j = 0; j < 8; ++j) {
        const float y = (x[j] - mean) * rstd * g[fb + j] + be[fb + j];
        o[j] = fmaxf(y, 0.f);
    }
    float* dst = &C[(size_t)row * (2 * NHID) + fb];
    *reinterpret_cast<float4*>(dst)     = make_float4(o[0], o[1], o[2], o[3]);
    *reinterpret_cast<float4*>(dst + 4) = make_float4(o[4], o[5], o[6], o[7]);
}

// ---------------------------------------------------------------------------
extern "C" void kernel_launch(void* const* d_in, const int* in_sizes, int n_in,
                              void* d_out, int out_size, void* d_ws, size_t ws_size,
                              hipStream_t stream)
{
    const float* x    = (const float*)d_in[0];
    const int*   rows = (const int*)  d_in[1];   // [4,E]
    const int*   cols = (const int*)  d_in[2];   // [4,E]
    const float* vals = (const float*)d_in[3];   // [4,E]
    const float* W0   = (const float*)d_in[4];
    const float* b0   = (const float*)d_in[5];
    const float* g0   = (const float*)d_in[6];
    const float* be0  = (const float*)d_in[7];
    const float* W1   = (const float*)d_in[8];
    const float* b1   = (const float*)d_in[9];
    const float* W2   = (const float*)d_in[10];
    const float* b2   = (const float*)d_in[11];
    const float* g2   = (const float*)d_in[12];
    const float* be2  = (const float*)d_in[13];
    const float* W3   = (const float*)d_in[14];
    const float* b3   = (const float*)d_in[15];
    const float* Wout = (const float*)d_in[16];
    const float* bout = (const float*)d_in[17];
    float* out = (float*)d_out;

    // workspace: A [N,256] | B [N,256] | C [N,512]   (204.8 MB total)
    float* A = (float*)d_ws;
    float* B = A + (size_t)N_NODES * NHID;
    float* C = B + (size_t)N_NODES * NHID;

    const dim3 blk(256);
    const dim3 g_gemm((N_NODES + 63) / 64, (NHID + 63) / 64);   // (782, 4)
    const dim3 g_head((N_NODES + 63) / 64, (NCLS + 63) / 64);   // (782, 2)
    const int  spmm_blocks = (E_EDGES * 64) / 256;              // 200000
    const int  ln_blocks   = (N_NODES * 64 + 255) / 256;        // 12500
    const size_t hidBytes  = (size_t)N_NODES * NHID * sizeof(float);

    // ---- layer 0: GraphSage(512 -> 256) + LN + ReLU ----
    gemm_bias_kernel<0><<<g_gemm, blk, 0, stream>>>(x, W0, b0, A, N_NODES, NFEAT, NHID);
    hipMemsetAsync(B, 0, hidBytes, stream);
    spmm_scatter_kernel<<<spmm_blocks, blk, 0, stream>>>(rows + 0 * E_EDGES, cols + 0 * E_EDGES,
                                                         vals + 0 * E_EDGES, A, B, E_EDGES);
    ln_concat_relu_kernel<<<ln_blocks, blk, 0, stream>>>(A, B, g0, be0, C, N_NODES);

    // ---- layer 1: GCN(512 -> 256) + ReLU (fused into next GEMM's A-load) ----
    gemm_bias_kernel<0><<<g_gemm, blk, 0, stream>>>(C, W1, b1, A, N_NODES, 2 * NHID, NHID);
    hipMemsetAsync(B, 0, hidBytes, stream);
    spmm_scatter_kernel<<<spmm_blocks, blk, 0, stream>>>(rows + 1 * E_EDGES, cols + 1 * E_EDGES,
                                                         vals + 1 * E_EDGES, A, B, E_EDGES);

    // ---- layer 2: GraphSage(256 -> 256) + LN + ReLU ----
    gemm_bias_kernel<1><<<g_gemm, blk, 0, stream>>>(B, W2, b2, A, N_NODES, NHID, NHID);
    hipMemsetAsync(B, 0, hidBytes, stream);
    spmm_scatter_kernel<<<spmm_blocks, blk, 0, stream>>>(rows + 2 * E_EDGES, cols + 2 * E_EDGES,
                                                         vals + 2 * E_EDGES, A, B, E_EDGES);
    ln_concat_relu_kernel<<<ln_blocks, blk, 0, stream>>>(A, B, g2, be2, C, N_NODES);

    // ---- layer 3: GCN(512 -> 256) + ReLU (fused into head GEMM's A-load) ----
    gemm_bias_kernel<0><<<g_gemm, blk, 0, stream>>>(C, W3, b3, A, N_NODES, 2 * NHID, NHID);
    hipMemsetAsync(B, 0, hidBytes, stream);
    spmm_scatter_kernel<<<spmm_blocks, blk, 0, stream>>>(rows + 3 * E_EDGES, cols + 3 * E_EDGES,
                                                         vals + 3 * E_EDGES, A, B, E_EDGES);

    // ---- output head: (N,256) @ (256,100) + bias ----
    gemm_bias_kernel<1><<<g_head, blk, 0, stream>>>(B, Wout, bout, out, N_NODES, NHID, NCLS);
}

// Round 2
// 1692.290 us; speedup vs baseline: 6.7314x; 6.7314x over previous
//
#include <hip/hip_runtime.h>

#define N_NODES 50000
#define E_EDGES 800000
#define NFEAT   512
#define NHID    256
#define NCLS    100
#define LN_EPS  1e-5f

// ---------------------------------------------------------------------------
// GEMM: C[M,Nc] = op(A[M,K]) @ W[K,Nc] + bias   (op = identity or relu)
// 64x64 tile, BK=16, 256 threads, 4x4 micro-tile per thread. fp32.
// ---------------------------------------------------------------------------
template<int RELU_A>
__global__ __launch_bounds__(256)
void gemm_bias_kernel(const float* __restrict__ A, const float* __restrict__ W,
                      const float* __restrict__ bias, float* __restrict__ C,
                      int M, int K, int Nc)
{
    __shared__ float As[16][68];   // [k][m], padded
    __shared__ float Ws[16][68];   // [k][n], padded

    const int tid = threadIdx.x;
    const int bm  = blockIdx.x * 64;
    const int bn  = blockIdx.y * 64;
    const int tm  = (tid >> 4) << 2;
    const int tn  = (tid & 15) << 2;

    const int ar = tid >> 2;
    const int ak = (tid & 3) << 2;
    const int wk = tid >> 4;
    const int wn = (tid & 15) << 2;

    float acc[4][4] = {{0.f,0.f,0.f,0.f},{0.f,0.f,0.f,0.f},
                       {0.f,0.f,0.f,0.f},{0.f,0.f,0.f,0.f}};

    for (int k0 = 0; k0 < K; k0 += 16) {
        {
            const int row = bm + ar;
            float4 v = make_float4(0.f, 0.f, 0.f, 0.f);
            if (row < M) {
                v = *reinterpret_cast<const float4*>(&A[(size_t)row * K + k0 + ak]);
                if (RELU_A) {
                    v.x = fmaxf(v.x, 0.f); v.y = fmaxf(v.y, 0.f);
                    v.z = fmaxf(v.z, 0.f); v.w = fmaxf(v.w, 0.f);
                }
            }
            As[ak + 0][ar] = v.x; As[ak + 1][ar] = v.y;
            As[ak + 2][ar] = v.z; As[ak + 3][ar] = v.w;
        }
        {
            const int col = bn + wn;
            float4 v = make_float4(0.f, 0.f, 0.f, 0.f);
            const float* wp = &W[(size_t)(k0 + wk) * Nc];
            if (col + 3 < Nc) {
                v = *reinterpret_cast<const float4*>(&wp[col]);
            } else if (col < Nc) {
                v.x = wp[col];
                if (col + 1 < Nc) v.y = wp[col + 1];
                if (col + 2 < Nc) v.z = wp[col + 2];
            }
            Ws[wk][wn + 0] = v.x; Ws[wk][wn + 1] = v.y;
            Ws[wk][wn + 2] = v.z; Ws[wk][wn + 3] = v.w;
        }
        __syncthreads();

        #pragma unroll
        for (int k = 0; k < 16; ++k) {
            const float a0 = As[k][tm + 0], a1 = As[k][tm + 1],
                        a2 = As[k][tm + 2], a3 = As[k][tm + 3];
            const float b0 = Ws[k][tn + 0], b1 = Ws[k][tn + 1],
                        b2 = Ws[k][tn + 2], b3 = Ws[k][tn + 3];
            acc[0][0] += a0 * b0; acc[0][1] += a0 * b1; acc[0][2] += a0 * b2; acc[0][3] += a0 * b3;
            acc[1][0] += a1 * b0; acc[1][1] += a1 * b1; acc[1][2] += a1 * b2; acc[1][3] += a1 * b3;
            acc[2][0] += a2 * b0; acc[2][1] += a2 * b1; acc[2][2] += a2 * b2; acc[2][3] += a2 * b3;
            acc[3][0] += a3 * b0; acc[3][1] += a3 * b1; acc[3][2] += a3 * b2; acc[3][3] += a3 * b3;
        }
        __syncthreads();
    }

    #pragma unroll
    for (int i = 0; i < 4; ++i) {
        const int row = bm + tm + i;
        if (row >= M) continue;
        #pragma unroll
        for (int j = 0; j < 4; ++j) {
            const int col = bn + tn + j;
            if (col < Nc)
                C[(size_t)row * Nc + col] = acc[i][j] + bias[col];
        }
    }
}

// ---------------------------------------------------------------------------
// Concat-GEMM: C[M,256] = concat([A1,A2],1)[M,512] @ W[512,256] + bias
// Same tiling; A-tile source switches at k0 == 256 (BK=16 divides 256).
// ---------------------------------------------------------------------------
__global__ __launch_bounds__(256)
void gemm_bias_concat_kernel(const float* __restrict__ A1, const float* __restrict__ A2,
                             const float* __restrict__ W, const float* __restrict__ bias,
                             float* __restrict__ C, int M)
{
    __shared__ float As[16][68];
    __shared__ float Ws[16][68];

    const int tid = threadIdx.x;
    const int bm  = blockIdx.x * 64;
    const int bn  = blockIdx.y * 64;
    const int tm  = (tid >> 4) << 2;
    const int tn  = (tid & 15) << 2;

    const int ar = tid >> 2;
    const int ak = (tid & 3) << 2;
    const int wk = tid >> 4;
    const int wn = (tid & 15) << 2;

    float acc[4][4] = {{0.f,0.f,0.f,0.f},{0.f,0.f,0.f,0.f},
                       {0.f,0.f,0.f,0.f},{0.f,0.f,0.f,0.f}};

    for (int k0 = 0; k0 < 2 * NHID; k0 += 16) {
        {
            const float* Asrc = (k0 < NHID) ? A1 : A2;
            const int kk = (k0 < NHID) ? k0 : k0 - NHID;
            const int row = bm + ar;
            float4 v = make_float4(0.f, 0.f, 0.f, 0.f);
            if (row < M)
                v = *reinterpret_cast<const float4*>(&Asrc[(size_t)row * NHID + kk + ak]);
            As[ak + 0][ar] = v.x; As[ak + 1][ar] = v.y;
            As[ak + 2][ar] = v.z; As[ak + 3][ar] = v.w;
        }
        {
            const float4 v = *reinterpret_cast<const float4*>(&W[(size_t)(k0 + wk) * NHID + bn + wn]);
            Ws[wk][wn + 0] = v.x; Ws[wk][wn + 1] = v.y;
            Ws[wk][wn + 2] = v.z; Ws[wk][wn + 3] = v.w;
        }
        __syncthreads();

        #pragma unroll
        for (int k = 0; k < 16; ++k) {
            const float a0 = As[k][tm + 0], a1 = As[k][tm + 1],
                        a2 = As[k][tm + 2], a3 = As[k][tm + 3];
            const float b0 = Ws[k][tn + 0], b1 = Ws[k][tn + 1],
                        b2 = Ws[k][tn + 2], b3 = Ws[k][tn + 3];
            acc[0][0] += a0 * b0; acc[0][1] += a0 * b1; acc[0][2] += a0 * b2; acc[0][3] += a0 * b3;
            acc[1][0] += a1 * b0; acc[1][1] += a1 * b1; acc[1][2] += a1 * b2; acc[1][3] += a1 * b3;
            acc[2][0] += a2 * b0; acc[2][1] += a2 * b1; acc[2][2] += a2 * b2; acc[2][3] += a2 * b3;
            acc[3][0] += a3 * b0; acc[3][1] += a3 * b1; acc[3][2] += a3 * b2; acc[3][3] += a3 * b3;
        }
        __syncthreads();
    }

    #pragma unroll
    for (int i = 0; i < 4; ++i) {
        const int row = bm + tm + i;
        if (row >= M) continue;
        #pragma unroll
        for (int j = 0; j < 4; ++j)
            C[(size_t)row * NHID + tn + j + bn] = acc[i][j] + bias[bn + tn + j];
    }
}

// ---------------------------------------------------------------------------
// CSR build: histogram -> exclusive scan -> stable-ish scatter
// ---------------------------------------------------------------------------
__global__ __launch_bounds__(256)
void histo_kernel(const int* __restrict__ rows, int* __restrict__ deg, int total)
{
    const int e = blockIdx.x * 256 + threadIdx.x;
    if (e >= total) return;
    const int a = e / E_EDGES;
    atomicAdd(&deg[a * N_NODES + rows[e]], 1);
}

// one block (1024 thr) per adjacency; deg is rewritten into cursor(=rowstart)
__global__ __launch_bounds__(1024)
void scan_kernel(int* __restrict__ deg, int* __restrict__ rowstart)
{
    __shared__ int sums[1024];
    const int a = blockIdx.x;
    int* d  = deg + (size_t)a * N_NODES;
    int* rs = rowstart + (size_t)a * (N_NODES + 1);

    const int t = threadIdx.x;
    const int chunk = (N_NODES + 1023) / 1024;   // 49
    const int base = t * chunk;

    int s = 0;
    for (int i = 0; i < chunk; ++i) {
        const int idx = base + i;
        if (idx < N_NODES) s += d[idx];
    }
    sums[t] = s;
    __syncthreads();
    for (int off = 1; off < 1024; off <<= 1) {
        int tmp = (t >= off) ? sums[t - off] : 0;
        __syncthreads();
        sums[t] += tmp;
        __syncthreads();
    }
    int run = sums[t] - s;   // exclusive prefix of this thread's chunk
    for (int i = 0; i < chunk; ++i) {
        const int idx = base + i;
        if (idx < N_NODES) {
            const int dv = d[idx];
            rs[idx] = run;
            d[idx]  = run;   // becomes cursor
            run += dv;
        }
    }
    if (t == 1023) rs[N_NODES] = E_EDGES;
}

__global__ __launch_bounds__(256)
void scatter_kernel(const int* __restrict__ rows, const int* __restrict__ cols,
                    const float* __restrict__ vals, int* __restrict__ cursor,
                    int* __restrict__ ccols, float* __restrict__ cvals, int total)
{
    const int e = blockIdx.x * 256 + threadIdx.x;
    if (e >= total) return;
    const int a = e / E_EDGES;
    const int p = atomicAdd(&cursor[a * N_NODES + rows[e]], 1);
    ccols[(size_t)a * E_EDGES + p] = cols[e];
    cvals[(size_t)a * E_EDGES + p] = vals[e];
}

// ---------------------------------------------------------------------------
// SpMM gather: out[r,:] = sum_j vals[j] * feat[cols[j],:]  over CSR row r.
// One wave per row; lane holds 4 consecutive floats.
// ---------------------------------------------------------------------------
__global__ __launch_bounds__(256)
void spmm_gather_kernel(const int* __restrict__ rowstart, const int* __restrict__ ccols,
                        const float* __restrict__ cvals, const float* __restrict__ feat,
                        float* __restrict__ out)
{
    const int gid  = blockIdx.x * 256 + threadIdx.x;
    const int row  = gid >> 6;
    const int lane = gid & 63;
    if (row >= N_NODES) return;

    const int s = rowstart[row];
    const int e = rowstart[row + 1];

    float4 acc = make_float4(0.f, 0.f, 0.f, 0.f);
    for (int j = s; j < e; ++j) {
        const int   c = ccols[j];
        const float v = cvals[j];
        const float4 f = *reinterpret_cast<const float4*>(&feat[(size_t)c * NHID + lane * 4]);
        acc.x += v * f.x; acc.y += v * f.y; acc.z += v * f.z; acc.w += v * f.w;
    }
    *reinterpret_cast<float4*>(&out[(size_t)row * NHID + lane * 4]) = acc;
}

// ---------------------------------------------------------------------------
// In-place LayerNorm over the virtual concat [A|B] (512 feats) + affine + ReLU.
// One wave per row; lanes 0..31 own A, 32..63 own B.
// ---------------------------------------------------------------------------
__global__ __launch_bounds__(256)
void ln_inplace_kernel(float* __restrict__ A, float* __restrict__ B,
                       const float* __restrict__ g, const float* __restrict__ be)
{
    const int gid  = blockIdx.x * 256 + threadIdx.x;
    const int row  = gid >> 6;
    const int lane = gid & 63;
    if (row >= N_NODES) return;

    float* src = (lane < 32) ? &A[(size_t)row * NHID + lane * 8]
                             : &B[(size_t)row * NHID + (lane - 32) * 8];
    const float4 v0 = *reinterpret_cast<const float4*>(src);
    const float4 v1 = *reinterpret_cast<const float4*>(src + 4);
    float x[8] = {v0.x, v0.y, v0.z, v0.w, v1.x, v1.y, v1.z, v1.w};

    float s = 0.f;
    #pragma unroll
    for (int j = 0; j < 8; ++j) s += x[j];
    #pragma unroll
    for (int m = 1; m < 64; m <<= 1) s += __shfl_xor(s, m, 64);
    const float mean = s * (1.f / 512.f);

    float sq = 0.f;
    #pragma unroll
    for (int j = 0; j < 8; ++j) { const float d = x[j] - mean; sq += d * d; }
    #pragma unroll
    for (int m = 1; m < 64; m <<= 1) sq += __shfl_xor(sq, m, 64);
    const float rstd = rsqrtf(sq * (1.f / 512.f) + LN_EPS);

    const int fb = lane * 8;   // 0..504 over the virtual 512
    float o[8];
    #pragma unroll
    for (int j = 0; j < 8; ++j) {
        const float y = (x[j] - mean) * rstd * g[fb + j] + be[fb + j];
        o[j] = fmaxf(y, 0.f);
    }
    *reinterpret_cast<float4*>(src)     = make_float4(o[0], o[1], o[2], o[3]);
    *reinterpret_cast<float4*>(src + 4) = make_float4(o[4], o[5], o[6], o[7]);
}

// ---------------------------------------------------------------------------
extern "C" void kernel_launch(void* const* d_in, const int* in_sizes, int n_in,
                              void* d_out, int out_size, void* d_ws, size_t ws_size,
                              hipStream_t stream)
{
    const float* x    = (const float*)d_in[0];
    const int*   rows = (const int*)  d_in[1];   // [4,E]
    const int*   cols = (const int*)  d_in[2];
    const float* vals = (const float*)d_in[3];
    const float* W0   = (const float*)d_in[4];
    const float* b0   = (const float*)d_in[5];
    const float* g0   = (const float*)d_in[6];
    const float* be0  = (const float*)d_in[7];
    const float* W1   = (const float*)d_in[8];
    const float* b1   = (const float*)d_in[9];
    const float* W2   = (const float*)d_in[10];
    const float* b2   = (const float*)d_in[11];
    const float* g2   = (const float*)d_in[12];
    const float* be2  = (const float*)d_in[13];
    const float* W3   = (const float*)d_in[14];
    const float* b3   = (const float*)d_in[15];
    const float* Wout = (const float*)d_in[16];
    const float* bout = (const float*)d_in[17];
    float* out = (float*)d_out;

    // ---- workspace layout (elements of 4 bytes, 256B-aligned segments) ----
    // deg/cursor[4N] | rowstart[4(N+1)] | ccols[4E] | cvals[4E] | A | B | T
    char* wsb = (char*)d_ws;
    size_t off = 0;
    auto carve = [&](size_t bytes) { void* p = wsb + off; off += (bytes + 255) & ~(size_t)255; return p; };
    int*   deg      = (int*)  carve((size_t)4 * N_NODES * 4);
    int*   rowstart = (int*)  carve((size_t)4 * (N_NODES + 1) * 4);
    int*   ccols    = (int*)  carve((size_t)4 * E_EDGES * 4);
    float* cvals    = (float*)carve((size_t)4 * E_EDGES * 4);
    float* A        = (float*)carve((size_t)N_NODES * NHID * 4);
    float* B        = (float*)carve((size_t)N_NODES * NHID * 4);
    float* T        = (float*)carve((size_t)N_NODES * NHID * 4);

    const dim3 blk(256);
    const dim3 g_gemm((N_NODES + 63) / 64, (NHID + 63) / 64);
    const dim3 g_head((N_NODES + 63) / 64, (NCLS + 63) / 64);
    const int  edge_blocks = (4 * E_EDGES + 255) / 256;          // 12500
    const int  row_blocks  = (N_NODES * 64 + 255) / 256;         // 12500

    // ---- CSR build for all 4 adjacencies ----
    hipMemsetAsync(deg, 0, (size_t)4 * N_NODES * 4, stream);
    histo_kernel<<<edge_blocks, blk, 0, stream>>>(rows, deg, 4 * E_EDGES);
    scan_kernel<<<4, 1024, 0, stream>>>(deg, rowstart);
    scatter_kernel<<<edge_blocks, blk, 0, stream>>>(rows, cols, vals, deg, ccols, cvals, 4 * E_EDGES);

    const int* rs0 = rowstart;
    const int* rs1 = rowstart + (N_NODES + 1);
    const int* rs2 = rowstart + 2 * (N_NODES + 1);
    const int* rs3 = rowstart + 3 * (N_NODES + 1);
    const int*   cc0 = ccols;                 const float* cv0 = cvals;
    const int*   cc1 = ccols + E_EDGES;       const float* cv1 = cvals + E_EDGES;
    const int*   cc2 = ccols + 2 * E_EDGES;   const float* cv2 = cvals + 2 * E_EDGES;
    const int*   cc3 = ccols + 3 * E_EDGES;   const float* cv3 = cvals + 3 * E_EDGES;

    // ---- layer 0: GraphSage(512->256) + LN(inplace) + ReLU ----
    gemm_bias_kernel<0><<<g_gemm, blk, 0, stream>>>(x, W0, b0, A, N_NODES, NFEAT, NHID);
    spmm_gather_kernel<<<row_blocks, blk, 0, stream>>>(rs0, cc0, cv0, A, B);
    ln_inplace_kernel<<<row_blocks, blk, 0, stream>>>(A, B, g0, be0);

    // ---- layer 1: GCN(concat 512->256) + ReLU (fused into next GEMM A-load) ----
    gemm_bias_concat_kernel<<<g_gemm, blk, 0, stream>>>(A, B, W1, b1, T, N_NODES);
    spmm_gather_kernel<<<row_blocks, blk, 0, stream>>>(rs1, cc1, cv1, T, A);

    // ---- layer 2: GraphSage(256->256) + LN(inplace) + ReLU ----
    gemm_bias_kernel<1><<<g_gemm, blk, 0, stream>>>(A, W2, b2, B, N_NODES, NHID, NHID);
    spmm_gather_kernel<<<row_blocks, blk, 0, stream>>>(rs2, cc2, cv2, B, T);
    ln_inplace_kernel<<<row_blocks, blk, 0, stream>>>(B, T, g2, be2);

    // ---- layer 3: GCN(concat 512->256) + ReLU (fused into head GEMM A-load) ----
    gemm_bias_concat_kernel<<<g_gemm, blk, 0, stream>>>(B, T, W3, b3, A, N_NODES);
    spmm_gather_kernel<<<row_blocks, blk, 0, stream>>>(rs3, cc3, cv3, A, B);

    // ---- output head: relu(B) @ Wout + bout ----
    gemm_bias_kernel<1><<<g_head, blk, 0, stream>>>(B, Wout, bout, out, N_NODES, NHID, NCLS);
}

// Round 3
// 1341.134 us; speedup vs baseline: 8.4939x; 1.2618x over previous
//
#include <hip/hip_runtime.h>

#define N_NODES 50000
#define E_EDGES 800000
#define NFEAT   512
#define NHID    256
#define NCLS    100
#define LN_EPS  1e-5f

typedef __attribute__((ext_vector_type(8))) short bf16x8;
typedef __attribute__((ext_vector_type(4))) float f32x4;

__device__ __forceinline__ ushort bf16_rne(float x) {
    unsigned u = __float_as_uint(x);
    unsigned r = u + 0x7FFFu + ((u >> 16) & 1u);
    return (ushort)(r >> 16);
}
__device__ __forceinline__ float bf16_to_f(ushort h) {
    return __uint_as_float(((unsigned)h) << 16);
}

// ---------------------------------------------------------------------------
// Weight split+transpose: W [K][Nc] fp32 -> WTh/WTl [NP][K] bf16 (zero-padded)
// ---------------------------------------------------------------------------
__global__ __launch_bounds__(256)
void wsplit_kernel(const float* __restrict__ W, ushort* __restrict__ WTh,
                   ushort* __restrict__ WTl, int K, int Nc, int NP)
{
    const int idx = blockIdx.x * 256 + threadIdx.x;
    if (idx >= NP * K) return;
    const int n = idx / K, k = idx - n * K;
    const float w = (n < Nc) ? W[(size_t)k * Nc + n] : 0.f;
    const ushort h = bf16_rne(w);
    WTh[idx] = h;
    WTl[idx] = bf16_rne(w - bf16_to_f(h));
}

// ---------------------------------------------------------------------------
// Split-3 bf16 MFMA GEMM:  C[M][Nc] = op(A)[M][K] @ B[K][Nc] + bias
// A = [A1 (first K1 cols) | A2 (rest)], both row-major fp32 (ld = part width).
// B given pre-split/transposed: BTh/BTl [NP][K] bf16.
// 128x128 tile, BK=32, 256 thr = 4 waves (2x2), wave tile 64x64 (4x4 frags).
// A converted fp32->(hi,lo) bf16 in registers during staging.
// ---------------------------------------------------------------------------
#define LDR 40   // padded LDS row length (ushorts); 80 B, 16B-aligned

template<int RELU_A>
__global__ __launch_bounds__(256)
void gemm_mfma_split3(const float* __restrict__ A1, const float* __restrict__ A2,
                      int K1, int K,
                      const ushort* __restrict__ BTh, const ushort* __restrict__ BTl,
                      const float* __restrict__ bias, float* __restrict__ C,
                      int M, int Nc)
{
    __shared__ __align__(16) ushort Ah[128 * LDR];
    __shared__ __align__(16) ushort Al[128 * LDR];
    __shared__ __align__(16) ushort Bh[128 * LDR];
    __shared__ __align__(16) ushort Bl[128 * LDR];

    const int tid = threadIdx.x;
    const int bm  = blockIdx.x * 128;
    const int bn  = blockIdx.y * 128;
    const int w   = tid >> 6;
    const int l   = tid & 63;
    const int wm  = (w >> 1) * 64;
    const int wn  = (w & 1) * 64;
    const int fr  = l & 15;
    const int fq  = l >> 4;

    const int sr = tid >> 1;           // staged row/col 0..127
    const int sh = (tid & 1) * 16;     // k-offset 0 or 16

    f32x4 acc[4][4];
    #pragma unroll
    for (int i = 0; i < 4; ++i)
        #pragma unroll
        for (int j = 0; j < 4; ++j) acc[i][j] = (f32x4){0.f, 0.f, 0.f, 0.f};

    const int NS = K / 32;
    for (int s = 0; s < NS; ++s) {
        const int k0 = s * 32;
        __syncthreads();

        // ---- stage A: 16 fp32 -> 16 (hi,lo) bf16 pairs ----
        {
            const float* src; int kk, ld;
            if (k0 < K1) { src = A1; kk = k0;      ld = K1;     }
            else         { src = A2; kk = k0 - K1; ld = K - K1; }
            const int row = bm + sr;
            float xv[16];
            if (row < M) {
                const float* p = &src[(size_t)row * ld + kk + sh];
                const float4 v0 = ((const float4*)p)[0];
                const float4 v1 = ((const float4*)p)[1];
                const float4 v2 = ((const float4*)p)[2];
                const float4 v3 = ((const float4*)p)[3];
                xv[0]=v0.x; xv[1]=v0.y; xv[2]=v0.z; xv[3]=v0.w;
                xv[4]=v1.x; xv[5]=v1.y; xv[6]=v1.z; xv[7]=v1.w;
                xv[8]=v2.x; xv[9]=v2.y; xv[10]=v2.z; xv[11]=v2.w;
                xv[12]=v3.x; xv[13]=v3.y; xv[14]=v3.z; xv[15]=v3.w;
            } else {
                #pragma unroll
                for (int j = 0; j < 16; ++j) xv[j] = 0.f;
            }
            if (RELU_A) {
                #pragma unroll
                for (int j = 0; j < 16; ++j) xv[j] = fmaxf(xv[j], 0.f);
            }
            bf16x8 h0, h1, l0, l1;
            #pragma unroll
            for (int j = 0; j < 8; ++j) {
                ushort ha = bf16_rne(xv[j]);
                ushort hb = bf16_rne(xv[j + 8]);
                h0[j] = (short)ha; h1[j] = (short)hb;
                l0[j] = (short)bf16_rne(xv[j]     - bf16_to_f(ha));
                l1[j] = (short)bf16_rne(xv[j + 8] - bf16_to_f(hb));
            }
            const int base = sr * LDR + sh;
            *(bf16x8*)&Ah[base]     = h0;
            *(bf16x8*)&Ah[base + 8] = h1;
            *(bf16x8*)&Al[base]     = l0;
            *(bf16x8*)&Al[base + 8] = l1;
        }
        // ---- stage B: copy pre-split transposed weights ----
        {
            const ushort* ph = &BTh[(size_t)(bn + sr) * K + k0 + sh];
            const ushort* pl = &BTl[(size_t)(bn + sr) * K + k0 + sh];
            const int base = sr * LDR + sh;
            *(bf16x8*)&Bh[base]     = *(const bf16x8*)ph;
            *(bf16x8*)&Bh[base + 8] = *(const bf16x8*)(ph + 8);
            *(bf16x8*)&Bl[base]     = *(const bf16x8*)pl;
            *(bf16x8*)&Bl[base + 8] = *(const bf16x8*)(pl + 8);
        }
        __syncthreads();

        // ---- fragments + 48 MFMA ----
        bf16x8 bhf[4], blf[4];
        #pragma unroll
        for (int nf = 0; nf < 4; ++nf) {
            const int addr = (wn + nf * 16 + fr) * LDR + fq * 8;
            bhf[nf] = *(const bf16x8*)&Bh[addr];
            blf[nf] = *(const bf16x8*)&Bl[addr];
        }
        #pragma unroll
        for (int mf = 0; mf < 4; ++mf) {
            const int addr = (wm + mf * 16 + fr) * LDR + fq * 8;
            const bf16x8 ahf = *(const bf16x8*)&Ah[addr];
            const bf16x8 alf = *(const bf16x8*)&Al[addr];
            #pragma unroll
            for (int nf = 0; nf < 4; ++nf) {
                acc[mf][nf] = __builtin_amdgcn_mfma_f32_16x16x32_bf16(ahf, bhf[nf], acc[mf][nf], 0, 0, 0);
                acc[mf][nf] = __builtin_amdgcn_mfma_f32_16x16x32_bf16(ahf, blf[nf], acc[mf][nf], 0, 0, 0);
                acc[mf][nf] = __builtin_amdgcn_mfma_f32_16x16x32_bf16(alf, bhf[nf], acc[mf][nf], 0, 0, 0);
            }
        }
    }

    // ---- epilogue: D col = lane&15, row = (lane>>4)*4 + reg ----
    #pragma unroll
    for (int mf = 0; mf < 4; ++mf) {
        #pragma unroll
        for (int r = 0; r < 4; ++r) {
            const int row = bm + wm + mf * 16 + fq * 4 + r;
            if (row >= M) continue;
            #pragma unroll
            for (int nf = 0; nf < 4; ++nf) {
                const int col = bn + wn + nf * 16 + fr;
                if (col < Nc)
                    C[(size_t)row * Nc + col] = acc[mf][nf][r] + bias[col];
            }
        }
    }
}

// ---------------------------------------------------------------------------
// CSR build
// ---------------------------------------------------------------------------
__global__ __launch_bounds__(256)
void histo_kernel(const int* __restrict__ rows, int* __restrict__ deg, int total)
{
    const int e = blockIdx.x * 256 + threadIdx.x;
    if (e >= total) return;
    const int a = e / E_EDGES;
    atomicAdd(&deg[a * N_NODES + rows[e]], 1);
}

__global__ __launch_bounds__(1024)
void scan_kernel(int* __restrict__ deg, int* __restrict__ rowstart)
{
    __shared__ int sums[1024];
    const int a = blockIdx.x;
    int* d  = deg + (size_t)a * N_NODES;
    int* rs = rowstart + (size_t)a * (N_NODES + 1);

    const int t = threadIdx.x;
    const int chunk = (N_NODES + 1023) / 1024;
    const int base = t * chunk;

    int s = 0;
    for (int i = 0; i < chunk; ++i) {
        const int idx = base + i;
        if (idx < N_NODES) s += d[idx];
    }
    sums[t] = s;
    __syncthreads();
    for (int off = 1; off < 1024; off <<= 1) {
        int tmp = (t >= off) ? sums[t - off] : 0;
        __syncthreads();
        sums[t] += tmp;
        __syncthreads();
    }
    int run = sums[t] - s;
    for (int i = 0; i < chunk; ++i) {
        const int idx = base + i;
        if (idx < N_NODES) {
            const int dv = d[idx];
            rs[idx] = run;
            d[idx]  = run;
            run += dv;
        }
    }
    if (t == 1023) rs[N_NODES] = E_EDGES;
}

__global__ __launch_bounds__(256)
void scatter_kernel(const int* __restrict__ rows, const int* __restrict__ cols,
                    const float* __restrict__ vals, int* __restrict__ cursor,
                    int2* __restrict__ cpk, int total)
{
    const int e = blockIdx.x * 256 + threadIdx.x;
    if (e >= total) return;
    const int a = e / E_EDGES;
    const int p = atomicAdd(&cursor[a * N_NODES + rows[e]], 1);
    cpk[(size_t)a * E_EDGES + p] = make_int2(cols[e], __float_as_int(vals[e]));
}

// ---------------------------------------------------------------------------
// SpMM gather over CSR: one wave per row, lane holds 4 consecutive floats.
// ---------------------------------------------------------------------------
__global__ __launch_bounds__(256)
void spmm_gather_kernel(const int* __restrict__ rowstart, const int2* __restrict__ cpk,
                        const float* __restrict__ feat, float* __restrict__ out)
{
    const int gid  = blockIdx.x * 256 + threadIdx.x;
    const int row  = gid >> 6;
    const int lane = gid & 63;
    if (row >= N_NODES) return;

    const int s = rowstart[row];
    const int e = rowstart[row + 1];

    float4 acc = make_float4(0.f, 0.f, 0.f, 0.f);
    for (int j = s; j < e; ++j) {
        const int2 ev = cpk[j];
        const float v = __int_as_float(ev.y);
        const float4 f = *reinterpret_cast<const float4*>(&feat[(size_t)ev.x * NHID + lane * 4]);
        acc.x += v * f.x; acc.y += v * f.y; acc.z += v * f.z; acc.w += v * f.w;
    }
    *reinterpret_cast<float4*>(&out[(size_t)row * NHID + lane * 4]) = acc;
}

// ---------------------------------------------------------------------------
// In-place LayerNorm over virtual concat [A|B] (512) + affine + ReLU.
// ---------------------------------------------------------------------------
__global__ __launch_bounds__(256)
void ln_inplace_kernel(float* __restrict__ A, float* __restrict__ B,
                       const float* __restrict__ g, const float* __restrict__ be)
{
    const int gid  = blockIdx.x * 256 + threadIdx.x;
    const int row  = gid >> 6;
    const int lane = gid & 63;
    if (row >= N_NODES) return;

    float* src = (lane < 32) ? &A[(size_t)row * NHID + lane * 8]
                             : &B[(size_t)row * NHID + (lane - 32) * 8];
    const float4 v0 = *reinterpret_cast<const float4*>(src);
    const float4 v1 = *reinterpret_cast<const float4*>(src + 4);
    float x[8] = {v0.x, v0.y, v0.z, v0.w, v1.x, v1.y, v1.z, v1.w};

    float s = 0.f;
    #pragma unroll
    for (int j = 0; j < 8; ++j) s += x[j];
    #pragma unroll
    for (int m = 1; m < 64; m <<= 1) s += __shfl_xor(s, m, 64);
    const float mean = s * (1.f / 512.f);

    float sq = 0.f;
    #pragma unroll
    for (int j = 0; j < 8; ++j) { const float d = x[j] - mean; sq += d * d; }
    #pragma unroll
    for (int m = 1; m < 64; m <<= 1) sq += __shfl_xor(sq, m, 64);
    const float rstd = rsqrtf(sq * (1.f / 512.f) + LN_EPS);

    const int fb = lane * 8;
    float o[8];
    #pragma unroll
    for (int j = 0; j < 8; ++j) {
        const float y = (x[j] - mean) * rstd * g[fb + j] + be[fb + j];
        o[j] = fmaxf(y, 0.f);
    }
    *reinterpret_cast<float4*>(src)     = make_float4(o[0], o[1], o[2], o[3]);
    *reinterpret_cast<float4*>(src + 4) = make_float4(o[4], o[5], o[6], o[7]);
}

// ---------------------------------------------------------------------------
extern "C" void kernel_launch(void* const* d_in, const int* in_sizes, int n_in,
                              void* d_out, int out_size, void* d_ws, size_t ws_size,
                              hipStream_t stream)
{
    const float* x    = (const float*)d_in[0];
    const int*   rows = (const int*)  d_in[1];
    const int*   cols = (const int*)  d_in[2];
    const float* vals = (const float*)d_in[3];
    const float* W0   = (const float*)d_in[4];
    const float* b0   = (const float*)d_in[5];
    const float* g0   = (const float*)d_in[6];
    const float* be0  = (const float*)d_in[7];
    const float* W1   = (const float*)d_in[8];
    const float* b1   = (const float*)d_in[9];
    const float* W2   = (const float*)d_in[10];
    const float* b2   = (const float*)d_in[11];
    const float* g2   = (const float*)d_in[12];
    const float* be2  = (const float*)d_in[13];
    const float* W3   = (const float*)d_in[14];
    const float* b3   = (const float*)d_in[15];
    const float* Wout = (const float*)d_in[16];
    const float* bout = (const float*)d_in[17];
    float* out = (float*)d_out;

    // ---- workspace carve ----
    char* wsb = (char*)d_ws;
    size_t off = 0;
    auto carve = [&](size_t bytes) { void* p = wsb + off; off += (bytes + 255) & ~(size_t)255; return p; };
    int*   deg      = (int*)  carve((size_t)4 * N_NODES * 4);
    int*   rowstart = (int*)  carve((size_t)4 * (N_NODES + 1) * 4);
    int2*  cpk      = (int2*) carve((size_t)4 * E_EDGES * 8);
    float* A        = (float*)carve((size_t)N_NODES * NHID * 4);
    float* B        = (float*)carve((size_t)N_NODES * NHID * 4);
    float* T        = (float*)carve((size_t)N_NODES * NHID * 4);
    // split/transposed weights (bf16 hi/lo): [NP][K]
    ushort* W0Th = (ushort*)carve((size_t)256 * 512 * 2);
    ushort* W0Tl = (ushort*)carve((size_t)256 * 512 * 2);
    ushort* W1Th = (ushort*)carve((size_t)256 * 512 * 2);
    ushort* W1Tl = (ushort*)carve((size_t)256 * 512 * 2);
    ushort* W2Th = (ushort*)carve((size_t)256 * 256 * 2);
    ushort* W2Tl = (ushort*)carve((size_t)256 * 256 * 2);
    ushort* W3Th = (ushort*)carve((size_t)256 * 512 * 2);
    ushort* W3Tl = (ushort*)carve((size_t)256 * 512 * 2);
    ushort* WoTh = (ushort*)carve((size_t)128 * 256 * 2);
    ushort* WoTl = (ushort*)carve((size_t)128 * 256 * 2);

    const dim3 blk(256);
    const dim3 g_gemm(391, 2);       // 128x128 tiles over 50000 x 256
    const dim3 g_head(391, 1);       // N padded to 128
    const int  edge_blocks = (4 * E_EDGES + 255) / 256;
    const int  row_blocks  = (N_NODES * 64 + 255) / 256;

    // ---- weight split (tiny) ----
    wsplit_kernel<<<(256*512 + 255)/256, blk, 0, stream>>>(W0,   W0Th, W0Tl, 512, 256, 256);
    wsplit_kernel<<<(256*512 + 255)/256, blk, 0, stream>>>(W1,   W1Th, W1Tl, 512, 256, 256);
    wsplit_kernel<<<(256*256 + 255)/256, blk, 0, stream>>>(W2,   W2Th, W2Tl, 256, 256, 256);
    wsplit_kernel<<<(256*512 + 255)/256, blk, 0, stream>>>(W3,   W3Th, W3Tl, 512, 256, 256);
    wsplit_kernel<<<(128*256 + 255)/256, blk, 0, stream>>>(Wout, WoTh, WoTl, 256, 100, 128);

    // ---- CSR build ----
    hipMemsetAsync(deg, 0, (size_t)4 * N_NODES * 4, stream);
    histo_kernel<<<edge_blocks, blk, 0, stream>>>(rows, deg, 4 * E_EDGES);
    scan_kernel<<<4, 1024, 0, stream>>>(deg, rowstart);
    scatter_kernel<<<edge_blocks, blk, 0, stream>>>(rows, cols, vals, deg, cpk, 4 * E_EDGES);

    const int* rs0 = rowstart;
    const int* rs1 = rowstart + (N_NODES + 1);
    const int* rs2 = rowstart + 2 * (N_NODES + 1);
    const int* rs3 = rowstart + 3 * (N_NODES + 1);
    const int2* c0 = cpk;
    const int2* c1 = cpk + E_EDGES;
    const int2* c2 = cpk + 2 * (size_t)E_EDGES;
    const int2* c3 = cpk + 3 * (size_t)E_EDGES;

    // ---- layer 0: GraphSage(512->256) + LN(inplace) + ReLU ----
    gemm_mfma_split3<0><<<g_gemm, blk, 0, stream>>>(x, x, 512, 512, W0Th, W0Tl, b0, A, N_NODES, 256);
    spmm_gather_kernel<<<row_blocks, blk, 0, stream>>>(rs0, c0, A, B);
    ln_inplace_kernel<<<row_blocks, blk, 0, stream>>>(A, B, g0, be0);

    // ---- layer 1: GCN(concat 512->256) ----
    gemm_mfma_split3<0><<<g_gemm, blk, 0, stream>>>(A, B, 256, 512, W1Th, W1Tl, b1, T, N_NODES, 256);
    spmm_gather_kernel<<<row_blocks, blk, 0, stream>>>(rs1, c1, T, A);

    // ---- layer 2: GraphSage(256->256), relu fused into A-stage ----
    gemm_mfma_split3<1><<<g_gemm, blk, 0, stream>>>(A, A, 256, 256, W2Th, W2Tl, b2, B, N_NODES, 256);
    spmm_gather_kernel<<<row_blocks, blk, 0, stream>>>(rs2, c2, B, T);
    ln_inplace_kernel<<<row_blocks, blk, 0, stream>>>(B, T, g2, be2);

    // ---- layer 3: GCN(concat 512->256) ----
    gemm_mfma_split3<0><<<g_gemm, blk, 0, stream>>>(B, T, 256, 512, W3Th, W3Tl, b3, A, N_NODES, 256);
    spmm_gather_kernel<<<row_blocks, blk, 0, stream>>>(rs3, c3, A, B);

    // ---- output head: relu(B) @ Wout + bout ----
    gemm_mfma_split3<1><<<g_head, blk, 0, stream>>>(B, B, 256, 256, WoTh, WoTl, bout, out, N_NODES, 100);
}

// Round 4
// 1123.596 us; speedup vs baseline: 10.1384x; 1.1936x over previous
//
#include <hip/hip_runtime.h>

#define N_NODES 50000
#define E_EDGES 800000
#define NFEAT   512
#define NHID    256
#define NCLS    100
#define LN_EPS  1e-5f

typedef __attribute__((ext_vector_type(8))) short bf16x8;
typedef __attribute__((ext_vector_type(4))) float f32x4;

__device__ __forceinline__ ushort bf16_rne(float x) {
    unsigned u = __float_as_uint(x);
    unsigned r = u + 0x7FFFu + ((u >> 16) & 1u);
    return (ushort)(r >> 16);
}
__device__ __forceinline__ float bf16_to_f(ushort h) {
    return __uint_as_float(((unsigned)h) << 16);
}

// ---------------------------------------------------------------------------
// Weight split+transpose: W [K][Nc] fp32 -> WTh/WTl [NP][K] bf16 (zero-padded)
// ---------------------------------------------------------------------------
__global__ __launch_bounds__(256)
void wsplit_kernel(const float* __restrict__ W, ushort* __restrict__ WTh,
                   ushort* __restrict__ WTl, int K, int Nc, int NP)
{
    const int idx = blockIdx.x * 256 + threadIdx.x;
    if (idx >= NP * K) return;
    const int n = idx / K, k = idx - n * K;
    const float w = (n < Nc) ? W[(size_t)k * Nc + n] : 0.f;
    const ushort h = bf16_rne(w);
    WTh[idx] = h;
    WTl[idx] = bf16_rne(w - bf16_to_f(h));
}

// ---------------------------------------------------------------------------
// Split-2 bf16 MFMA GEMM:  C = op(A)[M][K] @ (Bh+Bl)[K][Nc] + bias
// A = [A1 (first K1 cols) | A2 (rest)], row-major fp32; converted to single
// bf16 in registers during staging. Weights pre-split hi/lo (exact-ish).
// 128x128 tile, BK=32, 4 waves (2x2), wave tile 64x64, 16x16x32 MFMA.
// Epilogue: optional fp32 C and/or bf16 Cbf writes.
// ---------------------------------------------------------------------------
#define LDR 40   // padded LDS row (ushorts); 80 B, 16B-aligned

template<int RELU_A, int WF32, int WBF>
__global__ __launch_bounds__(256)
void gemm_mfma_split2(const float* __restrict__ A1, const float* __restrict__ A2,
                      int K1, int K,
                      const ushort* __restrict__ BTh, const ushort* __restrict__ BTl,
                      const float* __restrict__ bias, float* __restrict__ C,
                      ushort* __restrict__ Cbf, int M, int Nc)
{
    __shared__ __align__(16) ushort Ah[128 * LDR];
    __shared__ __align__(16) ushort Bh[128 * LDR];
    __shared__ __align__(16) ushort Bl[128 * LDR];

    const int tid = threadIdx.x;
    const int bm  = blockIdx.x * 128;
    const int bn  = blockIdx.y * 128;
    const int w   = tid >> 6;
    const int l   = tid & 63;
    const int wm  = (w >> 1) * 64;
    const int wn  = (w & 1) * 64;
    const int fr  = l & 15;
    const int fq  = l >> 4;

    const int sr = tid >> 1;           // staged row/col 0..127
    const int sh = (tid & 1) * 16;     // k-offset 0 or 16

    f32x4 acc[4][4];
    #pragma unroll
    for (int i = 0; i < 4; ++i)
        #pragma unroll
        for (int j = 0; j < 4; ++j) acc[i][j] = (f32x4){0.f, 0.f, 0.f, 0.f};

    const int NS = K / 32;
    for (int s = 0; s < NS; ++s) {
        const int k0 = s * 32;
        __syncthreads();

        // ---- stage A: 16 fp32 -> 16 bf16 ----
        {
            const float* src; int kk, ld;
            if (k0 < K1) { src = A1; kk = k0;      ld = K1;     }
            else         { src = A2; kk = k0 - K1; ld = K - K1; }
            const int row = bm + sr;
            float xv[16];
            if (row < M) {
                const float* p = &src[(size_t)row * ld + kk + sh];
                const float4 v0 = ((const float4*)p)[0];
                const float4 v1 = ((const float4*)p)[1];
                const float4 v2 = ((const float4*)p)[2];
                const float4 v3 = ((const float4*)p)[3];
                xv[0]=v0.x; xv[1]=v0.y; xv[2]=v0.z; xv[3]=v0.w;
                xv[4]=v1.x; xv[5]=v1.y; xv[6]=v1.z; xv[7]=v1.w;
                xv[8]=v2.x; xv[9]=v2.y; xv[10]=v2.z; xv[11]=v2.w;
                xv[12]=v3.x; xv[13]=v3.y; xv[14]=v3.z; xv[15]=v3.w;
            } else {
                #pragma unroll
                for (int j = 0; j < 16; ++j) xv[j] = 0.f;
            }
            if (RELU_A) {
                #pragma unroll
                for (int j = 0; j < 16; ++j) xv[j] = fmaxf(xv[j], 0.f);
            }
            bf16x8 h0, h1;
            #pragma unroll
            for (int j = 0; j < 8; ++j) {
                h0[j] = (short)bf16_rne(xv[j]);
                h1[j] = (short)bf16_rne(xv[j + 8]);
            }
            const int base = sr * LDR + sh;
            *(bf16x8*)&Ah[base]     = h0;
            *(bf16x8*)&Ah[base + 8] = h1;
        }
        // ---- stage B: copy pre-split transposed weights ----
        {
            const ushort* ph = &BTh[(size_t)(bn + sr) * K + k0 + sh];
            const ushort* pl = &BTl[(size_t)(bn + sr) * K + k0 + sh];
            const int base = sr * LDR + sh;
            *(bf16x8*)&Bh[base]     = *(const bf16x8*)ph;
            *(bf16x8*)&Bh[base + 8] = *(const bf16x8*)(ph + 8);
            *(bf16x8*)&Bl[base]     = *(const bf16x8*)pl;
            *(bf16x8*)&Bl[base + 8] = *(const bf16x8*)(pl + 8);
        }
        __syncthreads();

        // ---- fragments + 32 MFMA ----
        bf16x8 bhf[4], blf[4];
        #pragma unroll
        for (int nf = 0; nf < 4; ++nf) {
            const int addr = (wn + nf * 16 + fr) * LDR + fq * 8;
            bhf[nf] = *(const bf16x8*)&Bh[addr];
            blf[nf] = *(const bf16x8*)&Bl[addr];
        }
        #pragma unroll
        for (int mf = 0; mf < 4; ++mf) {
            const int addr = (wm + mf * 16 + fr) * LDR + fq * 8;
            const bf16x8 ahf = *(const bf16x8*)&Ah[addr];
            #pragma unroll
            for (int nf = 0; nf < 4; ++nf) {
                acc[mf][nf] = __builtin_amdgcn_mfma_f32_16x16x32_bf16(ahf, bhf[nf], acc[mf][nf], 0, 0, 0);
                acc[mf][nf] = __builtin_amdgcn_mfma_f32_16x16x32_bf16(ahf, blf[nf], acc[mf][nf], 0, 0, 0);
            }
        }
    }

    // ---- epilogue: D col = lane&15, row = (lane>>4)*4 + reg ----
    #pragma unroll
    for (int mf = 0; mf < 4; ++mf) {
        #pragma unroll
        for (int r = 0; r < 4; ++r) {
            const int row = bm + wm + mf * 16 + fq * 4 + r;
            if (row >= M) continue;
            #pragma unroll
            for (int nf = 0; nf < 4; ++nf) {
                const int col = bn + wn + nf * 16 + fr;
                if (col < Nc) {
                    const float v = acc[mf][nf][r] + bias[col];
                    if (WF32) C[(size_t)row * Nc + col] = v;
                    if (WBF)  Cbf[(size_t)row * Nc + col] = bf16_rne(v);
                }
            }
        }
    }
}

// ---------------------------------------------------------------------------
// CSR build
// ---------------------------------------------------------------------------
__global__ __launch_bounds__(256)
void histo_kernel(const int* __restrict__ rows, int* __restrict__ deg, int total)
{
    const int e = blockIdx.x * 256 + threadIdx.x;
    if (e >= total) return;
    const int a = e / E_EDGES;
    atomicAdd(&deg[a * N_NODES + rows[e]], 1);
}

__global__ __launch_bounds__(1024)
void scan_kernel(int* __restrict__ deg, int* __restrict__ rowstart)
{
    __shared__ int sums[1024];
    const int a = blockIdx.x;
    int* d  = deg + (size_t)a * N_NODES;
    int* rs = rowstart + (size_t)a * (N_NODES + 1);

    const int t = threadIdx.x;
    const int chunk = (N_NODES + 1023) / 1024;
    const int base = t * chunk;

    int s = 0;
    for (int i = 0; i < chunk; ++i) {
        const int idx = base + i;
        if (idx < N_NODES) s += d[idx];
    }
    sums[t] = s;
    __syncthreads();
    for (int off = 1; off < 1024; off <<= 1) {
        int tmp = (t >= off) ? sums[t - off] : 0;
        __syncthreads();
        sums[t] += tmp;
        __syncthreads();
    }
    int run = sums[t] - s;
    for (int i = 0; i < chunk; ++i) {
        const int idx = base + i;
        if (idx < N_NODES) {
            const int dv = d[idx];
            rs[idx] = run;
            d[idx]  = run;
            run += dv;
        }
    }
    if (t == 1023) rs[N_NODES] = E_EDGES;
}

__global__ __launch_bounds__(256)
void scatter_kernel(const int* __restrict__ rows, const int* __restrict__ cols,
                    const float* __restrict__ vals, int* __restrict__ cursor,
                    int2* __restrict__ cpk, int total)
{
    const int e = blockIdx.x * 256 + threadIdx.x;
    if (e >= total) return;
    const int a = e / E_EDGES;
    const int p = atomicAdd(&cursor[a * N_NODES + rows[e]], 1);
    cpk[(size_t)a * E_EDGES + p] = make_int2(cols[e], __float_as_int(vals[e]));
}

// ---------------------------------------------------------------------------
// SpMM gather over CSR, bf16 feat: one wave per row, lane holds 4 bf16 (8B).
// fp32 accumulate, fp32 out. 2-way unrolled for load pipelining.
// ---------------------------------------------------------------------------
__global__ __launch_bounds__(256)
void spmm_gather_bf16(const int* __restrict__ rowstart, const int2* __restrict__ cpk,
                      const ushort* __restrict__ feat, float* __restrict__ out)
{
    const int gid  = blockIdx.x * 256 + threadIdx.x;
    const int row  = gid >> 6;
    const int lane = gid & 63;
    if (row >= N_NODES) return;

    const int s = rowstart[row];
    const int e = rowstart[row + 1];

    float4 acc0 = make_float4(0.f, 0.f, 0.f, 0.f);
    float4 acc1 = make_float4(0.f, 0.f, 0.f, 0.f);
    int j = s;
    for (; j + 1 < e; j += 2) {
        const int2 ea = cpk[j];
        const int2 eb = cpk[j + 1];
        const float va = __int_as_float(ea.y);
        const float vb = __int_as_float(eb.y);
        const ushort4 fa = *reinterpret_cast<const ushort4*>(&feat[(size_t)ea.x * NHID + lane * 4]);
        const ushort4 fb = *reinterpret_cast<const ushort4*>(&feat[(size_t)eb.x * NHID + lane * 4]);
        acc0.x += va * bf16_to_f(fa.x); acc0.y += va * bf16_to_f(fa.y);
        acc0.z += va * bf16_to_f(fa.z); acc0.w += va * bf16_to_f(fa.w);
        acc1.x += vb * bf16_to_f(fb.x); acc1.y += vb * bf16_to_f(fb.y);
        acc1.z += vb * bf16_to_f(fb.z); acc1.w += vb * bf16_to_f(fb.w);
    }
    if (j < e) {
        const int2 ea = cpk[j];
        const float va = __int_as_float(ea.y);
        const ushort4 fa = *reinterpret_cast<const ushort4*>(&feat[(size_t)ea.x * NHID + lane * 4]);
        acc0.x += va * bf16_to_f(fa.x); acc0.y += va * bf16_to_f(fa.y);
        acc0.z += va * bf16_to_f(fa.z); acc0.w += va * bf16_to_f(fa.w);
    }
    acc0.x += acc1.x; acc0.y += acc1.y; acc0.z += acc1.z; acc0.w += acc1.w;
    *reinterpret_cast<float4*>(&out[(size_t)row * NHID + lane * 4]) = acc0;
}

// ---------------------------------------------------------------------------
// In-place LayerNorm over virtual concat [A|B] (512) + affine + ReLU.
// ---------------------------------------------------------------------------
__global__ __launch_bounds__(256)
void ln_inplace_kernel(float* __restrict__ A, float* __restrict__ B,
                       const float* __restrict__ g, const float* __restrict__ be)
{
    const int gid  = blockIdx.x * 256 + threadIdx.x;
    const int row  = gid >> 6;
    const int lane = gid & 63;
    if (row >= N_NODES) return;

    float* src = (lane < 32) ? &A[(size_t)row * NHID + lane * 8]
                             : &B[(size_t)row * NHID + (lane - 32) * 8];
    const float4 v0 = *reinterpret_cast<const float4*>(src);
    const float4 v1 = *reinterpret_cast<const float4*>(src + 4);
    float x[8] = {v0.x, v0.y, v0.z, v0.w, v1.x, v1.y, v1.z, v1.w};

    float s = 0.f;
    #pragma unroll
    for (int j = 0; j < 8; ++j) s += x[j];
    #pragma unroll
    for (int m = 1; m < 64; m <<= 1) s += __shfl_xor(s, m, 64);
    const float mean = s * (1.f / 512.f);

    float sq = 0.f;
    #pragma unroll
    for (int j = 0; j < 8; ++j) { const float d = x[j] - mean; sq += d * d; }
    #pragma unroll
    for (int m = 1; m < 64; m <<= 1) sq += __shfl_xor(sq, m, 64);
    const float rstd = rsqrtf(sq * (1.f / 512.f) + LN_EPS);

    const int fb = lane * 8;
    float o[8];
    #pragma unroll
    for (int j = 0; j < 8; ++j) {
        const float y = (x[j] - mean) * rstd * g[fb + j] + be[fb + j];
        o[j] = fmaxf(y, 0.f);
    }
    *reinterpret_cast<float4*>(src)     = make_float4(o[0], o[1], o[2], o[3]);
    *reinterpret_cast<float4*>(src + 4) = make_float4(o[4], o[5], o[6], o[7]);
}

// ---------------------------------------------------------------------------
extern "C" void kernel_launch(void* const* d_in, const int* in_sizes, int n_in,
                              void* d_out, int out_size, void* d_ws, size_t ws_size,
                              hipStream_t stream)
{
    const float* x    = (const float*)d_in[0];
    const int*   rows = (const int*)  d_in[1];
    const int*   cols = (const int*)  d_in[2];
    const float* vals = (const float*)d_in[3];
    const float* W0   = (const float*)d_in[4];
    const float* b0   = (const float*)d_in[5];
    const float* g0   = (const float*)d_in[6];
    const float* be0  = (const float*)d_in[7];
    const float* W1   = (const float*)d_in[8];
    const float* b1   = (const float*)d_in[9];
    const float* W2   = (const float*)d_in[10];
    const float* b2   = (const float*)d_in[11];
    const float* g2   = (const float*)d_in[12];
    const float* be2  = (const float*)d_in[13];
    const float* W3   = (const float*)d_in[14];
    const float* b3   = (const float*)d_in[15];
    const float* Wout = (const float*)d_in[16];
    const float* bout = (const float*)d_in[17];
    float* out = (float*)d_out;

    // ---- workspace carve ----
    char* wsb = (char*)d_ws;
    size_t off = 0;
    auto carve = [&](size_t bytes) { void* p = wsb + off; off += (bytes + 255) & ~(size_t)255; return p; };
    int*    deg      = (int*)   carve((size_t)4 * N_NODES * 4);
    int*    rowstart = (int*)   carve((size_t)4 * (N_NODES + 1) * 4);
    int2*   cpk      = (int2*)  carve((size_t)4 * E_EDGES * 8);
    float*  A        = (float*) carve((size_t)N_NODES * NHID * 4);
    float*  B        = (float*) carve((size_t)N_NODES * NHID * 4);
    float*  T        = (float*) carve((size_t)N_NODES * NHID * 4);
    ushort* Fbf      = (ushort*)carve((size_t)N_NODES * NHID * 2);   // shared bf16 feat
    ushort* W0Th = (ushort*)carve((size_t)256 * 512 * 2);
    ushort* W0Tl = (ushort*)carve((size_t)256 * 512 * 2);
    ushort* W1Th = (ushort*)carve((size_t)256 * 512 * 2);
    ushort* W1Tl = (ushort*)carve((size_t)256 * 512 * 2);
    ushort* W2Th = (ushort*)carve((size_t)256 * 256 * 2);
    ushort* W2Tl = (ushort*)carve((size_t)256 * 256 * 2);
    ushort* W3Th = (ushort*)carve((size_t)256 * 512 * 2);
    ushort* W3Tl = (ushort*)carve((size_t)256 * 512 * 2);
    ushort* WoTh = (ushort*)carve((size_t)128 * 256 * 2);
    ushort* WoTl = (ushort*)carve((size_t)128 * 256 * 2);

    const dim3 blk(256);
    const dim3 g_gemm(391, 2);
    const dim3 g_head(391, 1);
    const int  edge_blocks = (4 * E_EDGES + 255) / 256;
    const int  row_blocks  = (N_NODES * 64 + 255) / 256;

    // ---- weight split (tiny) ----
    wsplit_kernel<<<(256*512 + 255)/256, blk, 0, stream>>>(W0,   W0Th, W0Tl, 512, 256, 256);
    wsplit_kernel<<<(256*512 + 255)/256, blk, 0, stream>>>(W1,   W1Th, W1Tl, 512, 256, 256);
    wsplit_kernel<<<(256*256 + 255)/256, blk, 0, stream>>>(W2,   W2Th, W2Tl, 256, 256, 256);
    wsplit_kernel<<<(256*512 + 255)/256, blk, 0, stream>>>(W3,   W3Th, W3Tl, 512, 256, 256);
    wsplit_kernel<<<(128*256 + 255)/256, blk, 0, stream>>>(Wout, WoTh, WoTl, 256, 100, 128);

    // ---- CSR build ----
    hipMemsetAsync(deg, 0, (size_t)4 * N_NODES * 4, stream);
    histo_kernel<<<edge_blocks, blk, 0, stream>>>(rows, deg, 4 * E_EDGES);
    scan_kernel<<<4, 1024, 0, stream>>>(deg, rowstart);
    scatter_kernel<<<edge_blocks, blk, 0, stream>>>(rows, cols, vals, deg, cpk, 4 * E_EDGES);

    const int* rs0 = rowstart;
    const int* rs1 = rowstart + (N_NODES + 1);
    const int* rs2 = rowstart + 2 * (N_NODES + 1);
    const int* rs3 = rowstart + 3 * (N_NODES + 1);
    const int2* c0 = cpk;
    const int2* c1 = cpk + E_EDGES;
    const int2* c2 = cpk + 2 * (size_t)E_EDGES;
    const int2* c3 = cpk + 3 * (size_t)E_EDGES;

    // ---- layer 0: GraphSage(512->256) + LN(inplace) + ReLU ----
    gemm_mfma_split2<0,1,1><<<g_gemm, blk, 0, stream>>>(x, x, 512, 512, W0Th, W0Tl, b0, A, Fbf, N_NODES, 256);
    spmm_gather_bf16<<<row_blocks, blk, 0, stream>>>(rs0, c0, Fbf, B);
    ln_inplace_kernel<<<row_blocks, blk, 0, stream>>>(A, B, g0, be0);

    // ---- layer 1: GCN(concat 512->256): bf16-only output ----
    gemm_mfma_split2<0,0,1><<<g_gemm, blk, 0, stream>>>(A, B, 256, 512, W1Th, W1Tl, b1, nullptr, Fbf, N_NODES, 256);
    spmm_gather_bf16<<<row_blocks, blk, 0, stream>>>(rs1, c1, Fbf, A);

    // ---- layer 2: GraphSage(256->256), relu fused into A-stage ----
    gemm_mfma_split2<1,1,1><<<g_gemm, blk, 0, stream>>>(A, A, 256, 256, W2Th, W2Tl, b2, B, Fbf, N_NODES, 256);
    spmm_gather_bf16<<<row_blocks, blk, 0, stream>>>(rs2, c2, Fbf, T);
    ln_inplace_kernel<<<row_blocks, blk, 0, stream>>>(B, T, g2, be2);

    // ---- layer 3: GCN(concat 512->256): bf16-only output ----
    gemm_mfma_split2<0,0,1><<<g_gemm, blk, 0, stream>>>(B, T, 256, 512, W3Th, W3Tl, b3, nullptr, Fbf, N_NODES, 256);
    spmm_gather_bf16<<<row_blocks, blk, 0, stream>>>(rs3, c3, Fbf, A);

    // ---- output head: relu(A) @ Wout + bout (fp32 only) ----
    gemm_mfma_split2<1,1,0><<<g_head, blk, 0, stream>>>(A, A, 256, 256, WoTh, WoTl, bout, out, nullptr, N_NODES, 100);
}

// Round 5
// 926.274 us; speedup vs baseline: 12.2982x; 1.2130x over previous
//
#include <hip/hip_runtime.h>

#define N_NODES 50000
#define E_EDGES 800000
#define NFEAT   512
#define NHID    256
#define NCLS    100
#define LN_EPS  1e-5f

#define NB     196     // row buckets of 256 rows
#define CHUNKA 6144    // edges per bin-pass block
#define CAPB   6656    // max edges per bucket in sort pass (exp 4096, +40 sigma)

typedef __attribute__((ext_vector_type(8))) short bf16x8;
typedef __attribute__((ext_vector_type(4))) float f32x4;

__device__ __forceinline__ ushort bf16_rne(float x) {
    unsigned u = __float_as_uint(x);
    unsigned r = u + 0x7FFFu + ((u >> 16) & 1u);
    return (ushort)(r >> 16);
}
__device__ __forceinline__ float bf16_to_f(ushort h) {
    return __uint_as_float(((unsigned)h) << 16);
}

// ---------------------------------------------------------------------------
// Weight split+transpose: W [K][Nc] fp32 -> WTh/WTl [NP][K] bf16 (zero-padded)
// ---------------------------------------------------------------------------
__global__ __launch_bounds__(256)
void wsplit_kernel(const float* __restrict__ W, ushort* __restrict__ WTh,
                   ushort* __restrict__ WTl, int K, int Nc, int NP)
{
    const int idx = blockIdx.x * 256 + threadIdx.x;
    if (idx >= NP * K) return;
    const int n = idx / K, k = idx - n * K;
    const float w = (n < Nc) ? W[(size_t)k * Nc + n] : 0.f;
    const ushort h = bf16_rne(w);
    WTh[idx] = h;
    WTl[idx] = bf16_rne(w - bf16_to_f(h));
}

// ---------------------------------------------------------------------------
// Split-2 bf16 MFMA GEMM (unchanged from R4)
// ---------------------------------------------------------------------------
#define LDR 40

template<int RELU_A, int WF32, int WBF>
__global__ __launch_bounds__(256)
void gemm_mfma_split2(const float* __restrict__ A1, const float* __restrict__ A2,
                      int K1, int K,
                      const ushort* __restrict__ BTh, const ushort* __restrict__ BTl,
                      const float* __restrict__ bias, float* __restrict__ C,
                      ushort* __restrict__ Cbf, int M, int Nc)
{
    __shared__ __align__(16) ushort Ah[128 * LDR];
    __shared__ __align__(16) ushort Bh[128 * LDR];
    __shared__ __align__(16) ushort Bl[128 * LDR];

    const int tid = threadIdx.x;
    const int bm  = blockIdx.x * 128;
    const int bn  = blockIdx.y * 128;
    const int w   = tid >> 6;
    const int l   = tid & 63;
    const int wm  = (w >> 1) * 64;
    const int wn  = (w & 1) * 64;
    const int fr  = l & 15;
    const int fq  = l >> 4;

    const int sr = tid >> 1;
    const int sh = (tid & 1) * 16;

    f32x4 acc[4][4];
    #pragma unroll
    for (int i = 0; i < 4; ++i)
        #pragma unroll
        for (int j = 0; j < 4; ++j) acc[i][j] = (f32x4){0.f, 0.f, 0.f, 0.f};

    const int NS = K / 32;
    for (int s = 0; s < NS; ++s) {
        const int k0 = s * 32;
        __syncthreads();

        {
            const float* src; int kk, ld;
            if (k0 < K1) { src = A1; kk = k0;      ld = K1;     }
            else         { src = A2; kk = k0 - K1; ld = K - K1; }
            const int row = bm + sr;
            float xv[16];
            if (row < M) {
                const float* p = &src[(size_t)row * ld + kk + sh];
                const float4 v0 = ((const float4*)p)[0];
                const float4 v1 = ((const float4*)p)[1];
                const float4 v2 = ((const float4*)p)[2];
                const float4 v3 = ((const float4*)p)[3];
                xv[0]=v0.x; xv[1]=v0.y; xv[2]=v0.z; xv[3]=v0.w;
                xv[4]=v1.x; xv[5]=v1.y; xv[6]=v1.z; xv[7]=v1.w;
                xv[8]=v2.x; xv[9]=v2.y; xv[10]=v2.z; xv[11]=v2.w;
                xv[12]=v3.x; xv[13]=v3.y; xv[14]=v3.z; xv[15]=v3.w;
            } else {
                #pragma unroll
                for (int j = 0; j < 16; ++j) xv[j] = 0.f;
            }
            if (RELU_A) {
                #pragma unroll
                for (int j = 0; j < 16; ++j) xv[j] = fmaxf(xv[j], 0.f);
            }
            bf16x8 h0, h1;
            #pragma unroll
            for (int j = 0; j < 8; ++j) {
                h0[j] = (short)bf16_rne(xv[j]);
                h1[j] = (short)bf16_rne(xv[j + 8]);
            }
            const int base = sr * LDR + sh;
            *(bf16x8*)&Ah[base]     = h0;
            *(bf16x8*)&Ah[base + 8] = h1;
        }
        {
            const ushort* ph = &BTh[(size_t)(bn + sr) * K + k0 + sh];
            const ushort* pl = &BTl[(size_t)(bn + sr) * K + k0 + sh];
            const int base = sr * LDR + sh;
            *(bf16x8*)&Bh[base]     = *(const bf16x8*)ph;
            *(bf16x8*)&Bh[base + 8] = *(const bf16x8*)(ph + 8);
            *(bf16x8*)&Bl[base]     = *(const bf16x8*)pl;
            *(bf16x8*)&Bl[base + 8] = *(const bf16x8*)(pl + 8);
        }
        __syncthreads();

        bf16x8 bhf[4], blf[4];
        #pragma unroll
        for (int nf = 0; nf < 4; ++nf) {
            const int addr = (wn + nf * 16 + fr) * LDR + fq * 8;
            bhf[nf] = *(const bf16x8*)&Bh[addr];
            blf[nf] = *(const bf16x8*)&Bl[addr];
        }
        #pragma unroll
        for (int mf = 0; mf < 4; ++mf) {
            const int addr = (wm + mf * 16 + fr) * LDR + fq * 8;
            const bf16x8 ahf = *(const bf16x8*)&Ah[addr];
            #pragma unroll
            for (int nf = 0; nf < 4; ++nf) {
                acc[mf][nf] = __builtin_amdgcn_mfma_f32_16x16x32_bf16(ahf, bhf[nf], acc[mf][nf], 0, 0, 0);
                acc[mf][nf] = __builtin_amdgcn_mfma_f32_16x16x32_bf16(ahf, blf[nf], acc[mf][nf], 0, 0, 0);
            }
        }
    }

    #pragma unroll
    for (int mf = 0; mf < 4; ++mf) {
        #pragma unroll
        for (int r = 0; r < 4; ++r) {
            const int row = bm + wm + mf * 16 + fq * 4 + r;
            if (row >= M) continue;
            #pragma unroll
            for (int nf = 0; nf < 4; ++nf) {
                const int col = bn + wn + nf * 16 + fr;
                if (col < Nc) {
                    const float v = acc[mf][nf][r] + bias[col];
                    if (WF32) C[(size_t)row * Nc + col] = v;
                    if (WBF)  Cbf[(size_t)row * Nc + col] = bf16_rne(v);
                }
            }
        }
    }
}

// ---------------------------------------------------------------------------
// CSR build: per-row histogram + scan (unchanged), then LDS-binned 2-pass sort
// ---------------------------------------------------------------------------
__global__ __launch_bounds__(256)
void histo_kernel(const int* __restrict__ rows, int* __restrict__ deg, int total)
{
    const int e = blockIdx.x * 256 + threadIdx.x;
    if (e >= total) return;
    const int a = e / E_EDGES;
    atomicAdd(&deg[a * N_NODES + rows[e]], 1);
}

__global__ __launch_bounds__(1024)
void scan_kernel(const int* __restrict__ deg, int* __restrict__ rowstart)
{
    __shared__ int sums[1024];
    const int a = blockIdx.x;
    const int* d  = deg + (size_t)a * N_NODES;
    int* rs = rowstart + (size_t)a * (N_NODES + 1);

    const int t = threadIdx.x;
    const int chunk = (N_NODES + 1023) / 1024;
    const int base = t * chunk;

    int s = 0;
    for (int i = 0; i < chunk; ++i) {
        const int idx = base + i;
        if (idx < N_NODES) s += d[idx];
    }
    sums[t] = s;
    __syncthreads();
    for (int off = 1; off < 1024; off <<= 1) {
        int tmp = (t >= off) ? sums[t - off] : 0;
        __syncthreads();
        sums[t] += tmp;
        __syncthreads();
    }
    int run = sums[t] - s;
    for (int i = 0; i < chunk; ++i) {
        const int idx = base + i;
        if (idx < N_NODES) {
            rs[idx] = run;
            run += d[idx];
        }
    }
    if (t == 1023) rs[N_NODES] = E_EDGES;
}

// Pass A: bin edges by row-bucket into staging with block-local LDS runs.
// Entry: x = (row<<16)|col (both < 2^16), y = val bits.
__global__ __launch_bounds__(256)
void bin_kernel(const int* __restrict__ rows, const int* __restrict__ cols,
                const float* __restrict__ vals, const int* __restrict__ rowstart,
                int* __restrict__ bcur, int2* __restrict__ est)
{
    __shared__ int cnt[NB];
    __shared__ int scn[256];
    __shared__ int cstart[NB];
    __shared__ int ccur[NB];
    __shared__ int gdst[NB];
    __shared__ __align__(16) int2 buf[CHUNKA];

    const int a  = blockIdx.y;
    const int e0 = blockIdx.x * CHUNKA;
    const int n  = min(CHUNKA, E_EDGES - e0);
    const int t  = threadIdx.x;
    const int*   rs = rowstart + (size_t)a * (N_NODES + 1);
    const int*   rp = rows + (size_t)a * E_EDGES + e0;
    const int*   cp = cols + (size_t)a * E_EDGES + e0;
    const float* vp = vals + (size_t)a * E_EDGES + e0;

    if (t < NB) cnt[t] = 0;
    __syncthreads();
    for (int i = t; i < n; i += 256) atomicAdd(&cnt[((unsigned)rp[i]) >> 8], 1);
    __syncthreads();

    scn[t] = (t < NB) ? cnt[t] : 0;
    __syncthreads();
    for (int off = 1; off < 256; off <<= 1) {
        const int v = (t >= off) ? scn[t - off] : 0;
        __syncthreads();
        scn[t] += v;
        __syncthreads();
    }
    if (t < NB) {
        const int ex = scn[t] - cnt[t];   // exclusive prefix
        cstart[t] = ex;
        ccur[t]   = ex;
        const int gb = atomicAdd(&bcur[a * NB + t], cnt[t]);
        gdst[t] = rs[t << 8] + gb - ex;
    }
    __syncthreads();

    for (int i = t; i < n; i += 256) {
        const unsigned r = (unsigned)rp[i];
        const int b = r >> 8;
        const int p = atomicAdd(&ccur[b], 1);
        buf[p] = make_int2((int)((r << 16) | (unsigned)cp[i]), __float_as_int(vp[i]));
    }
    __syncthreads();

    int2* eo = est + (size_t)a * E_EDGES;
    for (int i = t; i < n; i += 256) {
        const int2 en = buf[i];
        const int b = ((unsigned)en.x) >> 24;
        eo[gdst[b] + i] = en;   // bucket runs: consecutive i -> consecutive addr
    }
}

// Pass B: counting-sort each bucket in LDS, emit final (col,val) CSR runs.
__global__ __launch_bounds__(256)
void sort_kernel(const int* __restrict__ rowstart, const int2* __restrict__ est,
                 int2* __restrict__ cpk)
{
    __shared__ int cur[257];
    __shared__ __align__(16) int2 sbuf[CAPB];

    const int a = blockIdx.y;
    const int b = blockIdx.x;
    const int t = threadIdx.x;
    const int r0 = b << 8;
    const int r1 = min(r0 + 256, N_NODES);
    const int* rs = rowstart + (size_t)a * (N_NODES + 1);
    const int base = rs[r0];
    const int end  = rs[r1];
    const int cnt  = end - base;

    for (int i = t; i <= r1 - r0; i += 256) cur[i] = rs[r0 + i] - base;
    __syncthreads();

    const int2* ei = est + (size_t)a * E_EDGES + base;
    int2*       co = cpk + (size_t)a * E_EDGES + base;

    if (cnt <= CAPB) {
        for (int i = t; i < cnt; i += 256) {
            const int2 en = ei[i];
            const int rl = (int)(((unsigned)en.x) >> 16) - r0;
            const int p = atomicAdd(&cur[rl], 1);
            sbuf[p] = make_int2(en.x & 0xFFFF, en.y);
        }
        __syncthreads();
        for (int i = t; i < cnt; i += 256) co[i] = sbuf[i];
    } else {   // statistically unreachable; correct slow path
        for (int i = t; i < cnt; i += 256) {
            const int2 en = ei[i];
            const int rl = (int)(((unsigned)en.x) >> 16) - r0;
            const int p = atomicAdd(&cur[rl], 1);
            co[p] = make_int2(en.x & 0xFFFF, en.y);
        }
    }
}

// ---------------------------------------------------------------------------
// SpMM gather over CSR, bf16 feat (unchanged)
// ---------------------------------------------------------------------------
__global__ __launch_bounds__(256)
void spmm_gather_bf16(const int* __restrict__ rowstart, const int2* __restrict__ cpk,
                      const ushort* __restrict__ feat, float* __restrict__ out)
{
    const int gid  = blockIdx.x * 256 + threadIdx.x;
    const int row  = gid >> 6;
    const int lane = gid & 63;
    if (row >= N_NODES) return;

    const int s = rowstart[row];
    const int e = rowstart[row + 1];

    float4 acc0 = make_float4(0.f, 0.f, 0.f, 0.f);
    float4 acc1 = make_float4(0.f, 0.f, 0.f, 0.f);
    int j = s;
    for (; j + 1 < e; j += 2) {
        const int2 ea = cpk[j];
        const int2 eb = cpk[j + 1];
        const float va = __int_as_float(ea.y);
        const float vb = __int_as_float(eb.y);
        const ushort4 fa = *reinterpret_cast<const ushort4*>(&feat[(size_t)ea.x * NHID + lane * 4]);
        const ushort4 fb = *reinterpret_cast<const ushort4*>(&feat[(size_t)eb.x * NHID + lane * 4]);
        acc0.x += va * bf16_to_f(fa.x); acc0.y += va * bf16_to_f(fa.y);
        acc0.z += va * bf16_to_f(fa.z); acc0.w += va * bf16_to_f(fa.w);
        acc1.x += vb * bf16_to_f(fb.x); acc1.y += vb * bf16_to_f(fb.y);
        acc1.z += vb * bf16_to_f(fb.z); acc1.w += vb * bf16_to_f(fb.w);
    }
    if (j < e) {
        const int2 ea = cpk[j];
        const float va = __int_as_float(ea.y);
        const ushort4 fa = *reinterpret_cast<const ushort4*>(&feat[(size_t)ea.x * NHID + lane * 4]);
        acc0.x += va * bf16_to_f(fa.x); acc0.y += va * bf16_to_f(fa.y);
        acc0.z += va * bf16_to_f(fa.z); acc0.w += va * bf16_to_f(fa.w);
    }
    acc0.x += acc1.x; acc0.y += acc1.y; acc0.z += acc1.z; acc0.w += acc1.w;
    *reinterpret_cast<float4*>(&out[(size_t)row * NHID + lane * 4]) = acc0;
}

// ---------------------------------------------------------------------------
// In-place LayerNorm over virtual concat [A|B] (512) + affine + ReLU.
// ---------------------------------------------------------------------------
__global__ __launch_bounds__(256)
void ln_inplace_kernel(float* __restrict__ A, float* __restrict__ B,
                       const float* __restrict__ g, const float* __restrict__ be)
{
    const int gid  = blockIdx.x * 256 + threadIdx.x;
    const int row  = gid >> 6;
    const int lane = gid & 63;
    if (row >= N_NODES) return;

    float* src = (lane < 32) ? &A[(size_t)row * NHID + lane * 8]
                             : &B[(size_t)row * NHID + (lane - 32) * 8];
    const float4 v0 = *reinterpret_cast<const float4*>(src);
    const float4 v1 = *reinterpret_cast<const float4*>(src + 4);
    float x[8] = {v0.x, v0.y, v0.z, v0.w, v1.x, v1.y, v1.z, v1.w};

    float s = 0.f;
    #pragma unroll
    for (int j = 0; j < 8; ++j) s += x[j];
    #pragma unroll
    for (int m = 1; m < 64; m <<= 1) s += __shfl_xor(s, m, 64);
    const float mean = s * (1.f / 512.f);

    float sq = 0.f;
    #pragma unroll
    for (int j = 0; j < 8; ++j) { const float d = x[j] - mean; sq += d * d; }
    #pragma unroll
    for (int m = 1; m < 64; m <<= 1) sq += __shfl_xor(sq, m, 64);
    const float rstd = rsqrtf(sq * (1.f / 512.f) + LN_EPS);

    const int fb = lane * 8;
    float o[8];
    #pragma unroll
    for (int j = 0; j < 8; ++j) {
        const float y = (x[j] - mean) * rstd * g[fb + j] + be[fb + j];
        o[j] = fmaxf(y, 0.f);
    }
    *reinterpret_cast<float4*>(src)     = make_float4(o[0], o[1], o[2], o[3]);
    *reinterpret_cast<float4*>(src + 4) = make_float4(o[4], o[5], o[6], o[7]);
}

// ---------------------------------------------------------------------------
extern "C" void kernel_launch(void* const* d_in, const int* in_sizes, int n_in,
                              void* d_out, int out_size, void* d_ws, size_t ws_size,
                              hipStream_t stream)
{
    const float* x    = (const float*)d_in[0];
    const int*   rows = (const int*)  d_in[1];
    const int*   cols = (const int*)  d_in[2];
    const float* vals = (const float*)d_in[3];
    const float* W0   = (const float*)d_in[4];
    const float* b0   = (const float*)d_in[5];
    const float* g0   = (const float*)d_in[6];
    const float* be0  = (const float*)d_in[7];
    const float* W1   = (const float*)d_in[8];
    const float* b1   = (const float*)d_in[9];
    const float* W2   = (const float*)d_in[10];
    const float* b2   = (const float*)d_in[11];
    const float* g2   = (const float*)d_in[12];
    const float* be2  = (const float*)d_in[13];
    const float* W3   = (const float*)d_in[14];
    const float* b3   = (const float*)d_in[15];
    const float* Wout = (const float*)d_in[16];
    const float* bout = (const float*)d_in[17];
    float* out = (float*)d_out;

    // ---- workspace carve ----
    char* wsb = (char*)d_ws;
    size_t off = 0;
    auto carve = [&](size_t bytes) { void* p = wsb + off; off += (bytes + 255) & ~(size_t)255; return p; };
    int*    deg      = (int*)   carve((size_t)4 * N_NODES * 4);
    int*    rowstart = (int*)   carve((size_t)4 * (N_NODES + 1) * 4);
    int*    bcur     = (int*)   carve((size_t)4 * NB * 4);
    int2*   cpk      = (int2*)  carve((size_t)4 * E_EDGES * 8);
    float*  A        = (float*) carve((size_t)N_NODES * NHID * 4);
    float*  B        = (float*) carve((size_t)N_NODES * NHID * 4);
    float*  T        = (float*) carve((size_t)N_NODES * NHID * 4);
    ushort* Fbf      = (ushort*)carve((size_t)N_NODES * NHID * 2);
    ushort* W0Th = (ushort*)carve((size_t)256 * 512 * 2);
    ushort* W0Tl = (ushort*)carve((size_t)256 * 512 * 2);
    ushort* W1Th = (ushort*)carve((size_t)256 * 512 * 2);
    ushort* W1Tl = (ushort*)carve((size_t)256 * 512 * 2);
    ushort* W2Th = (ushort*)carve((size_t)256 * 256 * 2);
    ushort* W2Tl = (ushort*)carve((size_t)256 * 256 * 2);
    ushort* W3Th = (ushort*)carve((size_t)256 * 512 * 2);
    ushort* W3Tl = (ushort*)carve((size_t)256 * 512 * 2);
    ushort* WoTh = (ushort*)carve((size_t)128 * 256 * 2);
    ushort* WoTl = (ushort*)carve((size_t)128 * 256 * 2);

    int2* est = (int2*)T;   // staging for bin pass; T unused until layer 2

    const dim3 blk(256);
    const dim3 g_gemm(391, 2);
    const dim3 g_head(391, 1);
    const dim3 g_bin((E_EDGES + CHUNKA - 1) / CHUNKA, 4);   // (131, 4)
    const dim3 g_sort(NB, 4);                               // (196, 4)
    const int  edge_blocks = (4 * E_EDGES + 255) / 256;
    const int  row_blocks  = (N_NODES * 64 + 255) / 256;

    // ---- weight split (tiny) ----
    wsplit_kernel<<<(256*512 + 255)/256, blk, 0, stream>>>(W0,   W0Th, W0Tl, 512, 256, 256);
    wsplit_kernel<<<(256*512 + 255)/256, blk, 0, stream>>>(W1,   W1Th, W1Tl, 512, 256, 256);
    wsplit_kernel<<<(256*256 + 255)/256, blk, 0, stream>>>(W2,   W2Th, W2Tl, 256, 256, 256);
    wsplit_kernel<<<(256*512 + 255)/256, blk, 0, stream>>>(W3,   W3Th, W3Tl, 512, 256, 256);
    wsplit_kernel<<<(128*256 + 255)/256, blk, 0, stream>>>(Wout, WoTh, WoTl, 256, 100, 128);

    // ---- CSR build: histo -> scan -> bin -> sort ----
    hipMemsetAsync(deg, 0, (size_t)4 * N_NODES * 4, stream);
    hipMemsetAsync(bcur, 0, (size_t)4 * NB * 4, stream);
    histo_kernel<<<edge_blocks, blk, 0, stream>>>(rows, deg, 4 * E_EDGES);
    scan_kernel<<<4, 1024, 0, stream>>>(deg, rowstart);
    bin_kernel<<<g_bin, blk, 0, stream>>>(rows, cols, vals, rowstart, bcur, est);
    sort_kernel<<<g_sort, blk, 0, stream>>>(rowstart, est, cpk);

    const int* rs0 = rowstart;
    const int* rs1 = rowstart + (N_NODES + 1);
    const int* rs2 = rowstart + 2 * (N_NODES + 1);
    const int* rs3 = rowstart + 3 * (N_NODES + 1);
    const int2* c0 = cpk;
    const int2* c1 = cpk + E_EDGES;
    const int2* c2 = cpk + 2 * (size_t)E_EDGES;
    const int2* c3 = cpk + 3 * (size_t)E_EDGES;

    // ---- layer 0: GraphSage(512->256) + LN(inplace) + ReLU ----
    gemm_mfma_split2<0,1,1><<<g_gemm, blk, 0, stream>>>(x, x, 512, 512, W0Th, W0Tl, b0, A, Fbf, N_NODES, 256);
    spmm_gather_bf16<<<row_blocks, blk, 0, stream>>>(rs0, c0, Fbf, B);
    ln_inplace_kernel<<<row_blocks, blk, 0, stream>>>(A, B, g0, be0);

    // ---- layer 1: GCN(concat 512->256): bf16-only output ----
    gemm_mfma_split2<0,0,1><<<g_gemm, blk, 0, stream>>>(A, B, 256, 512, W1Th, W1Tl, b1, nullptr, Fbf, N_NODES, 256);
    spmm_gather_bf16<<<row_blocks, blk, 0, stream>>>(rs1, c1, Fbf, A);

    // ---- layer 2: GraphSage(256->256), relu fused into A-stage ----
    gemm_mfma_split2<1,1,1><<<g_gemm, blk, 0, stream>>>(A, A, 256, 256, W2Th, W2Tl, b2, B, Fbf, N_NODES, 256);
    spmm_gather_bf16<<<row_blocks, blk, 0, stream>>>(rs2, c2, Fbf, T);
    ln_inplace_kernel<<<row_blocks, blk, 0, stream>>>(B, T, g2, be2);

    // ---- layer 3: GCN(concat 512->256): bf16-only output ----
    gemm_mfma_split2<0,0,1><<<g_gemm, blk, 0, stream>>>(B, T, 256, 512, W3Th, W3Tl, b3, nullptr, Fbf, N_NODES, 256);
    spmm_gather_bf16<<<row_blocks, blk, 0, stream>>>(rs3, c3, Fbf, A);

    // ---- output head: relu(A) @ Wout + bout (fp32 only) ----
    gemm_mfma_split2<1,1,0><<<g_head, blk, 0, stream>>>(A, A, 256, 256, WoTh, WoTl, bout, out, nullptr, N_NODES, 100);
}

// Round 6
// 635.545 us; speedup vs baseline: 17.9240x; 1.4574x over previous
//
#include <hip/hip_runtime.h>

#define N_NODES 50000
#define E_EDGES 800000
#define NFEAT   512
#define NHID    256
#define NCLS    100
#define LN_EPS  1e-5f

#define NB     196     // row buckets of 256 rows
#define CHUNKA 6144    // edges per bin-pass block
#define CAPB   6656    // slots per bucket (exp 4096, sigma 64 -> +40 sigma)

typedef __attribute__((ext_vector_type(8))) short bf16x8;
typedef __attribute__((ext_vector_type(4))) float f32x4;

__device__ __forceinline__ ushort bf16_rne(float x) {
    unsigned u = __float_as_uint(x);
    unsigned r = u + 0x7FFFu + ((u >> 16) & 1u);
    return (ushort)(r >> 16);
}
__device__ __forceinline__ float bf16_to_f(ushort h) {
    return __uint_as_float(((unsigned)h) << 16);
}

// ---------------------------------------------------------------------------
// Weight split+transpose: W [K][Nc] fp32 -> WTh/WTl [NP][K] bf16 (zero-padded)
// ---------------------------------------------------------------------------
__global__ __launch_bounds__(256)
void wsplit_kernel(const float* __restrict__ W, ushort* __restrict__ WTh,
                   ushort* __restrict__ WTl, int K, int Nc, int NP)
{
    const int idx = blockIdx.x * 256 + threadIdx.x;
    if (idx >= NP * K) return;
    const int n = idx / K, k = idx - n * K;
    const float w = (n < Nc) ? W[(size_t)k * Nc + n] : 0.f;
    const ushort h = bf16_rne(w);
    WTh[idx] = h;
    WTl[idx] = bf16_rne(w - bf16_to_f(h));
}

// ---------------------------------------------------------------------------
// Split-2 bf16 MFMA GEMM:  C = A[M][K] @ (Bh+Bl)[K][Nc] + bias
// A = [A1 | A2] row-major; AF32: fp32 source converted in-reg, else bf16 copy.
// 128x128 tile, BK=32, 4 waves (2x2), wave tile 64x64, 16x16x32 MFMA.
// ---------------------------------------------------------------------------
#define LDR 40

template<int AF32, int WF32, int WBF>
__global__ __launch_bounds__(256)
void gemm_mfma_split2(const void* __restrict__ A1v, const void* __restrict__ A2v,
                      int K1, int K,
                      const ushort* __restrict__ BTh, const ushort* __restrict__ BTl,
                      const float* __restrict__ bias, float* __restrict__ C,
                      ushort* __restrict__ Cbf, int M, int Nc)
{
    __shared__ __align__(16) ushort Ah[128 * LDR];
    __shared__ __align__(16) ushort Bh[128 * LDR];
    __shared__ __align__(16) ushort Bl[128 * LDR];

    const int tid = threadIdx.x;
    const int bm  = blockIdx.x * 128;
    const int bn  = blockIdx.y * 128;
    const int w   = tid >> 6;
    const int l   = tid & 63;
    const int wm  = (w >> 1) * 64;
    const int wn  = (w & 1) * 64;
    const int fr  = l & 15;
    const int fq  = l >> 4;

    const int sr = tid >> 1;
    const int sh = (tid & 1) * 16;

    f32x4 acc[4][4];
    #pragma unroll
    for (int i = 0; i < 4; ++i)
        #pragma unroll
        for (int j = 0; j < 4; ++j) acc[i][j] = (f32x4){0.f, 0.f, 0.f, 0.f};

    const int NS = K / 32;
    for (int s = 0; s < NS; ++s) {
        const int k0 = s * 32;
        __syncthreads();

        // ---- stage A ----
        {
            const int row = bm + sr;
            bf16x8 h0, h1;
            if (AF32) {
                const float* src; int kk, ld;
                if (k0 < K1) { src = (const float*)A1v; kk = k0;      ld = K1;     }
                else         { src = (const float*)A2v; kk = k0 - K1; ld = K - K1; }
                float xv[16];
                if (row < M) {
                    const float* p = &src[(size_t)row * ld + kk + sh];
                    const float4 v0 = ((const float4*)p)[0];
                    const float4 v1 = ((const float4*)p)[1];
                    const float4 v2 = ((const float4*)p)[2];
                    const float4 v3 = ((const float4*)p)[3];
                    xv[0]=v0.x; xv[1]=v0.y; xv[2]=v0.z; xv[3]=v0.w;
                    xv[4]=v1.x; xv[5]=v1.y; xv[6]=v1.z; xv[7]=v1.w;
                    xv[8]=v2.x; xv[9]=v2.y; xv[10]=v2.z; xv[11]=v2.w;
                    xv[12]=v3.x; xv[13]=v3.y; xv[14]=v3.z; xv[15]=v3.w;
                } else {
                    #pragma unroll
                    for (int j = 0; j < 16; ++j) xv[j] = 0.f;
                }
                #pragma unroll
                for (int j = 0; j < 8; ++j) {
                    h0[j] = (short)bf16_rne(xv[j]);
                    h1[j] = (short)bf16_rne(xv[j + 8]);
                }
            } else {
                const ushort* src; int kk, ld;
                if (k0 < K1) { src = (const ushort*)A1v; kk = k0;      ld = K1;     }
                else         { src = (const ushort*)A2v; kk = k0 - K1; ld = K - K1; }
                if (row < M) {
                    const ushort* p = &src[(size_t)row * ld + kk + sh];
                    h0 = *(const bf16x8*)p;
                    h1 = *(const bf16x8*)(p + 8);
                } else {
                    h0 = (bf16x8){0,0,0,0,0,0,0,0};
                    h1 = (bf16x8){0,0,0,0,0,0,0,0};
                }
            }
            const int base = sr * LDR + sh;
            *(bf16x8*)&Ah[base]     = h0;
            *(bf16x8*)&Ah[base + 8] = h1;
        }
        // ---- stage B ----
        {
            const ushort* ph = &BTh[(size_t)(bn + sr) * K + k0 + sh];
            const ushort* pl = &BTl[(size_t)(bn + sr) * K + k0 + sh];
            const int base = sr * LDR + sh;
            *(bf16x8*)&Bh[base]     = *(const bf16x8*)ph;
            *(bf16x8*)&Bh[base + 8] = *(const bf16x8*)(ph + 8);
            *(bf16x8*)&Bl[base]     = *(const bf16x8*)pl;
            *(bf16x8*)&Bl[base + 8] = *(const bf16x8*)(pl + 8);
        }
        __syncthreads();

        bf16x8 bhf[4], blf[4];
        #pragma unroll
        for (int nf = 0; nf < 4; ++nf) {
            const int addr = (wn + nf * 16 + fr) * LDR + fq * 8;
            bhf[nf] = *(const bf16x8*)&Bh[addr];
            blf[nf] = *(const bf16x8*)&Bl[addr];
        }
        #pragma unroll
        for (int mf = 0; mf < 4; ++mf) {
            const int addr = (wm + mf * 16 + fr) * LDR + fq * 8;
            const bf16x8 ahf = *(const bf16x8*)&Ah[addr];
            #pragma unroll
            for (int nf = 0; nf < 4; ++nf) {
                acc[mf][nf] = __builtin_amdgcn_mfma_f32_16x16x32_bf16(ahf, bhf[nf], acc[mf][nf], 0, 0, 0);
                acc[mf][nf] = __builtin_amdgcn_mfma_f32_16x16x32_bf16(ahf, blf[nf], acc[mf][nf], 0, 0, 0);
            }
        }
    }

    #pragma unroll
    for (int mf = 0; mf < 4; ++mf) {
        #pragma unroll
        for (int r = 0; r < 4; ++r) {
            const int row = bm + wm + mf * 16 + fq * 4 + r;
            if (row >= M) continue;
            #pragma unroll
            for (int nf = 0; nf < 4; ++nf) {
                const int col = bn + wn + nf * 16 + fr;
                if (col < Nc) {
                    const float v = acc[mf][nf][r] + bias[col];
                    if (WF32) C[(size_t)row * Nc + col] = v;
                    if (WBF)  Cbf[(size_t)row * Nc + col] = bf16_rne(v);
                }
            }
        }
    }
}

// ---------------------------------------------------------------------------
// CSR build, no global histogram:
//   bin   : chunk -> LDS bucket-group -> est[bucket*CAPB + cursor] runs
//   bscan : 196-bucket exclusive prefix per adjacency
//   sort  : bucket in LDS -> row histogram+scan -> writes rowstart + CSR
// ---------------------------------------------------------------------------
__global__ __launch_bounds__(256)
void bin_kernel(const int* __restrict__ rows, const int* __restrict__ cols,
                const float* __restrict__ vals, int* __restrict__ bcur,
                int2* __restrict__ est)
{
    __shared__ int cnt[NB];
    __shared__ int scn[256];
    __shared__ int cstart[NB];
    __shared__ int ccur[NB];
    __shared__ int garr[NB];
    __shared__ __align__(16) int2 buf[CHUNKA];

    const int a  = blockIdx.y;
    const int e0 = blockIdx.x * CHUNKA;
    const int n  = min(CHUNKA, E_EDGES - e0);
    const int t  = threadIdx.x;
    const int*   rp = rows + (size_t)a * E_EDGES + e0;
    const int*   cp = cols + (size_t)a * E_EDGES + e0;
    const float* vp = vals + (size_t)a * E_EDGES + e0;

    if (t < NB) cnt[t] = 0;
    __syncthreads();
    for (int i = t; i < n; i += 256) atomicAdd(&cnt[((unsigned)rp[i]) >> 8], 1);
    __syncthreads();

    scn[t] = (t < NB) ? cnt[t] : 0;
    __syncthreads();
    for (int off = 1; off < 256; off <<= 1) {
        const int v = (t >= off) ? scn[t - off] : 0;
        __syncthreads();
        scn[t] += v;
        __syncthreads();
    }
    if (t < NB) {
        const int ex = scn[t] - cnt[t];
        cstart[t] = ex;
        ccur[t]   = ex;
        garr[t]   = atomicAdd(&bcur[a * NB + t], cnt[t]);
    }
    __syncthreads();

    for (int i = t; i < n; i += 256) {
        const unsigned r = (unsigned)rp[i];
        const int b = r >> 8;
        const int p = atomicAdd(&ccur[b], 1);
        buf[p] = make_int2((int)((r << 16) | (unsigned)cp[i]), __float_as_int(vp[i]));
    }
    __syncthreads();

    for (int i = t; i < n; i += 256) {
        const int2 en = buf[i];
        const int b = ((unsigned)en.x) >> 24;
        const int slot = garr[b] + (i - cstart[b]);
        if (slot < CAPB)   // statistically unreachable guard
            est[((size_t)(a * NB + b)) * CAPB + slot] = en;
    }
}

__global__ __launch_bounds__(256)
void bscan_kernel(const int* __restrict__ bcur, int* __restrict__ bbase)
{
    __shared__ int s[256];
    const int a = blockIdx.x;
    const int t = threadIdx.x;
    const int v = (t < NB) ? bcur[a * NB + t] : 0;
    s[t] = v;
    __syncthreads();
    for (int off = 1; off < 256; off <<= 1) {
        const int u = (t >= off) ? s[t - off] : 0;
        __syncthreads();
        s[t] += u;
        __syncthreads();
    }
    if (t < NB) bbase[a * NB + t] = s[t] - v;
}

__global__ __launch_bounds__(256)
void sort_kernel(const int* __restrict__ bcur, const int* __restrict__ bbase,
                 const int2* __restrict__ est, int2* __restrict__ cpk,
                 int* __restrict__ rowstart)
{
    __shared__ __align__(16) int2 sbuf[CAPB];
    __shared__ __align__(16) int2 obuf[CAPB];
    __shared__ int cnt[256];
    __shared__ int scn[256];
    __shared__ int cur[256];

    const int a = blockIdx.y;
    const int b = blockIdx.x;
    const int t = threadIdx.x;
    const int nb = min(bcur[a * NB + b], CAPB);
    const size_t slots = ((size_t)(a * NB + b)) * CAPB;

    for (int i = t; i < nb; i += 256) sbuf[i] = est[slots + i];
    cnt[t] = 0;
    __syncthreads();
    for (int i = t; i < nb; i += 256)
        atomicAdd(&cnt[(((unsigned)sbuf[i].x) >> 16) & 255], 1);
    __syncthreads();

    scn[t] = cnt[t];
    __syncthreads();
    for (int off = 1; off < 256; off <<= 1) {
        const int v = (t >= off) ? scn[t - off] : 0;
        __syncthreads();
        scn[t] += v;
        __syncthreads();
    }
    const int excl = scn[t] - cnt[t];
    cur[t] = excl;

    const int bb = bbase[a * NB + b];
    const int r0 = b << 8;
    if (r0 + t < N_NODES)
        rowstart[(size_t)a * (N_NODES + 1) + r0 + t] = bb + excl;
    if (b == NB - 1 && t == 0)
        rowstart[(size_t)a * (N_NODES + 1) + N_NODES] = E_EDGES;
    __syncthreads();

    for (int i = t; i < nb; i += 256) {
        const int2 en = sbuf[i];
        const int r = (((unsigned)en.x) >> 16) & 255;
        const int p = atomicAdd(&cur[r], 1);
        obuf[p] = make_int2(en.x & 0xFFFF, en.y);
    }
    __syncthreads();

    int2* co = cpk + (size_t)a * E_EDGES + bb;
    for (int i = t; i < nb; i += 256) co[i] = obuf[i];
}

// ---------------------------------------------------------------------------
// SpMM gather over CSR, bf16 feat -> bf16 out (optional fused relu).
// One wave per row; lane holds 4 bf16 (8B). 4-deep unroll.
// ---------------------------------------------------------------------------
template<int RELU>
__global__ __launch_bounds__(256)
void spmm_gather_bf16(const int* __restrict__ rowstart, const int2* __restrict__ cpk,
                      const ushort* __restrict__ feat, ushort* __restrict__ out)
{
    const int gid  = blockIdx.x * 256 + threadIdx.x;
    const int row  = gid >> 6;
    const int lane = gid & 63;
    if (row >= N_NODES) return;

    const int s = rowstart[row];
    const int e = rowstart[row + 1];

    float4 acc0 = make_float4(0.f, 0.f, 0.f, 0.f);
    float4 acc1 = make_float4(0.f, 0.f, 0.f, 0.f);
    float4 acc2 = make_float4(0.f, 0.f, 0.f, 0.f);
    float4 acc3 = make_float4(0.f, 0.f, 0.f, 0.f);
    int j = s;
    for (; j + 3 < e; j += 4) {
        const int2 e0 = cpk[j],     e1 = cpk[j + 1];
        const int2 e2 = cpk[j + 2], e3 = cpk[j + 3];
        const ushort4 f0 = *(const ushort4*)&feat[(size_t)e0.x * NHID + lane * 4];
        const ushort4 f1 = *(const ushort4*)&feat[(size_t)e1.x * NHID + lane * 4];
        const ushort4 f2 = *(const ushort4*)&feat[(size_t)e2.x * NHID + lane * 4];
        const ushort4 f3 = *(const ushort4*)&feat[(size_t)e3.x * NHID + lane * 4];
        const float v0 = __int_as_float(e0.y), v1 = __int_as_float(e1.y);
        const float v2 = __int_as_float(e2.y), v3 = __int_as_float(e3.y);
        acc0.x += v0 * bf16_to_f(f0.x); acc0.y += v0 * bf16_to_f(f0.y);
        acc0.z += v0 * bf16_to_f(f0.z); acc0.w += v0 * bf16_to_f(f0.w);
        acc1.x += v1 * bf16_to_f(f1.x); acc1.y += v1 * bf16_to_f(f1.y);
        acc1.z += v1 * bf16_to_f(f1.z); acc1.w += v1 * bf16_to_f(f1.w);
        acc2.x += v2 * bf16_to_f(f2.x); acc2.y += v2 * bf16_to_f(f2.y);
        acc2.z += v2 * bf16_to_f(f2.z); acc2.w += v2 * bf16_to_f(f2.w);
        acc3.x += v3 * bf16_to_f(f3.x); acc3.y += v3 * bf16_to_f(f3.y);
        acc3.z += v3 * bf16_to_f(f3.z); acc3.w += v3 * bf16_to_f(f3.w);
    }
    for (; j < e; ++j) {
        const int2 ea = cpk[j];
        const float va = __int_as_float(ea.y);
        const ushort4 fa = *(const ushort4*)&feat[(size_t)ea.x * NHID + lane * 4];
        acc0.x += va * bf16_to_f(fa.x); acc0.y += va * bf16_to_f(fa.y);
        acc0.z += va * bf16_to_f(fa.z); acc0.w += va * bf16_to_f(fa.w);
    }
    float ox = acc0.x + acc1.x + acc2.x + acc3.x;
    float oy = acc0.y + acc1.y + acc2.y + acc3.y;
    float oz = acc0.z + acc1.z + acc2.z + acc3.z;
    float ow = acc0.w + acc1.w + acc2.w + acc3.w;
    if (RELU) {
        ox = fmaxf(ox, 0.f); oy = fmaxf(oy, 0.f);
        oz = fmaxf(oz, 0.f); ow = fmaxf(ow, 0.f);
    }
    ushort4 o;
    o.x = bf16_rne(ox); o.y = bf16_rne(oy);
    o.z = bf16_rne(oz); o.w = bf16_rne(ow);
    *(ushort4*)&out[(size_t)row * NHID + lane * 4] = o;
}

// ---------------------------------------------------------------------------
// In-place LayerNorm over virtual concat [A|B] (512 bf16) + affine + ReLU.
// ---------------------------------------------------------------------------
__global__ __launch_bounds__(256)
void ln_inplace_bf16(ushort* __restrict__ A, ushort* __restrict__ B,
                     const float* __restrict__ g, const float* __restrict__ be)
{
    const int gid  = blockIdx.x * 256 + threadIdx.x;
    const int row  = gid >> 6;
    const int lane = gid & 63;
    if (row >= N_NODES) return;

    ushort* src = (lane < 32) ? &A[(size_t)row * NHID + lane * 8]
                              : &B[(size_t)row * NHID + (lane - 32) * 8];
    const ushort4 a0 = ((const ushort4*)src)[0];
    const ushort4 a1 = ((const ushort4*)src)[1];
    float x[8] = {bf16_to_f(a0.x), bf16_to_f(a0.y), bf16_to_f(a0.z), bf16_to_f(a0.w),
                  bf16_to_f(a1.x), bf16_to_f(a1.y), bf16_to_f(a1.z), bf16_to_f(a1.w)};

    float s = 0.f;
    #pragma unroll
    for (int j = 0; j < 8; ++j) s += x[j];
    #pragma unroll
    for (int m = 1; m < 64; m <<= 1) s += __shfl_xor(s, m, 64);
    const float mean = s * (1.f / 512.f);

    float sq = 0.f;
    #pragma unroll
    for (int j = 0; j < 8; ++j) { const float d = x[j] - mean; sq += d * d; }
    #pragma unroll
    for (int m = 1; m < 64; m <<= 1) sq += __shfl_xor(sq, m, 64);
    const float rstd = rsqrtf(sq * (1.f / 512.f) + LN_EPS);

    const int fb = lane * 8;
    ushort4 o0, o1;
    float o[8];
    #pragma unroll
    for (int j = 0; j < 8; ++j)
        o[j] = fmaxf((x[j] - mean) * rstd * g[fb + j] + be[fb + j], 0.f);
    o0.x = bf16_rne(o[0]); o0.y = bf16_rne(o[1]); o0.z = bf16_rne(o[2]); o0.w = bf16_rne(o[3]);
    o1.x = bf16_rne(o[4]); o1.y = bf16_rne(o[5]); o1.z = bf16_rne(o[6]); o1.w = bf16_rne(o[7]);
    ((ushort4*)src)[0] = o0;
    ((ushort4*)src)[1] = o1;
}

// ---------------------------------------------------------------------------
extern "C" void kernel_launch(void* const* d_in, const int* in_sizes, int n_in,
                              void* d_out, int out_size, void* d_ws, size_t ws_size,
                              hipStream_t stream)
{
    const float* x    = (const float*)d_in[0];
    const int*   rows = (const int*)  d_in[1];
    const int*   cols = (const int*)  d_in[2];
    const float* vals = (const float*)d_in[3];
    const float* W0   = (const float*)d_in[4];
    const float* b0   = (const float*)d_in[5];
    const float* g0   = (const float*)d_in[6];
    const float* be0  = (const float*)d_in[7];
    const float* W1   = (const float*)d_in[8];
    const float* b1   = (const float*)d_in[9];
    const float* W2   = (const float*)d_in[10];
    const float* b2   = (const float*)d_in[11];
    const float* g2   = (const float*)d_in[12];
    const float* be2  = (const float*)d_in[13];
    const float* W3   = (const float*)d_in[14];
    const float* b3   = (const float*)d_in[15];
    const float* Wout = (const float*)d_in[16];
    const float* bout = (const float*)d_in[17];
    float* out = (float*)d_out;

    // ---- workspace carve ----
    char* wsb = (char*)d_ws;
    size_t off = 0;
    auto carve = [&](size_t bytes) { void* p = wsb + off; off += (bytes + 255) & ~(size_t)255; return p; };
    int*    rowstart = (int*)   carve((size_t)4 * (N_NODES + 1) * 4);
    int*    bcur     = (int*)   carve((size_t)4 * NB * 4);
    int*    bbase    = (int*)   carve((size_t)4 * NB * 4);
    int2*   cpk      = (int2*)  carve((size_t)4 * E_EDGES * 8);
    int2*   est      = (int2*)  carve((size_t)4 * NB * CAPB * 8);
    ushort* Af       = (ushort*)carve((size_t)N_NODES * NHID * 2);
    ushort* Bf       = (ushort*)carve((size_t)N_NODES * NHID * 2);
    ushort* Tf       = (ushort*)carve((size_t)N_NODES * NHID * 2);
    ushort* W0Th = (ushort*)carve((size_t)256 * 512 * 2);
    ushort* W0Tl = (ushort*)carve((size_t)256 * 512 * 2);
    ushort* W1Th = (ushort*)carve((size_t)256 * 512 * 2);
    ushort* W1Tl = (ushort*)carve((size_t)256 * 512 * 2);
    ushort* W2Th = (ushort*)carve((size_t)256 * 256 * 2);
    ushort* W2Tl = (ushort*)carve((size_t)256 * 256 * 2);
    ushort* W3Th = (ushort*)carve((size_t)256 * 512 * 2);
    ushort* W3Tl = (ushort*)carve((size_t)256 * 512 * 2);
    ushort* WoTh = (ushort*)carve((size_t)128 * 256 * 2);
    ushort* WoTl = (ushort*)carve((size_t)128 * 256 * 2);

    const dim3 blk(256);
    const dim3 g_gemm(391, 2);
    const dim3 g_head(391, 1);
    const dim3 g_bin((E_EDGES + CHUNKA - 1) / CHUNKA, 4);   // (131, 4)
    const dim3 g_sort(NB, 4);                               // (196, 4)
    const int  row_blocks = (N_NODES * 64 + 255) / 256;     // 12500

    // ---- weight split (tiny) ----
    wsplit_kernel<<<(256*512 + 255)/256, blk, 0, stream>>>(W0,   W0Th, W0Tl, 512, 256, 256);
    wsplit_kernel<<<(256*512 + 255)/256, blk, 0, stream>>>(W1,   W1Th, W1Tl, 512, 256, 256);
    wsplit_kernel<<<(256*256 + 255)/256, blk, 0, stream>>>(W2,   W2Th, W2Tl, 256, 256, 256);
    wsplit_kernel<<<(256*512 + 255)/256, blk, 0, stream>>>(W3,   W3Th, W3Tl, 512, 256, 256);
    wsplit_kernel<<<(128*256 + 255)/256, blk, 0, stream>>>(Wout, WoTh, WoTl, 256, 100, 128);

    // ---- CSR build: bin -> bucket scan -> sort (writes rowstart) ----
    hipMemsetAsync(bcur, 0, (size_t)4 * NB * 4, stream);
    bin_kernel<<<g_bin, blk, 0, stream>>>(rows, cols, vals, bcur, est);
    bscan_kernel<<<4, blk, 0, stream>>>(bcur, bbase);
    sort_kernel<<<g_sort, blk, 0, stream>>>(bcur, bbase, est, cpk, rowstart);

    const int* rs0 = rowstart;
    const int* rs1 = rowstart + (N_NODES + 1);
    const int* rs2 = rowstart + 2 * (N_NODES + 1);
    const int* rs3 = rowstart + 3 * (N_NODES + 1);
    const int2* c0 = cpk;
    const int2* c1 = cpk + E_EDGES;
    const int2* c2 = cpk + 2 * (size_t)E_EDGES;
    const int2* c3 = cpk + 3 * (size_t)E_EDGES;

    // ---- layer 0: GraphSage(512->256): x(fp32) -> Af; agg -> Bf; LN inplace ----
    gemm_mfma_split2<1,0,1><<<g_gemm, blk, 0, stream>>>(x, x, 512, 512, W0Th, W0Tl, b0, nullptr, Af, N_NODES, 256);
    spmm_gather_bf16<0><<<row_blocks, blk, 0, stream>>>(rs0, c0, Af, Bf);
    ln_inplace_bf16<<<row_blocks, blk, 0, stream>>>(Af, Bf, g0, be0);

    // ---- layer 1: GCN(concat [Af|Bf] 512->256) -> Tf; spmm+relu -> Af ----
    gemm_mfma_split2<0,0,1><<<g_gemm, blk, 0, stream>>>(Af, Bf, 256, 512, W1Th, W1Tl, b1, nullptr, Tf, N_NODES, 256);
    spmm_gather_bf16<1><<<row_blocks, blk, 0, stream>>>(rs1, c1, Tf, Af);

    // ---- layer 2: GraphSage(256->256): Af -> Tf; agg -> Bf; LN inplace ----
    gemm_mfma_split2<0,0,1><<<g_gemm, blk, 0, stream>>>(Af, Af, 256, 256, W2Th, W2Tl, b2, nullptr, Tf, N_NODES, 256);
    spmm_gather_bf16<0><<<row_blocks, blk, 0, stream>>>(rs2, c2, Tf, Bf);
    ln_inplace_bf16<<<row_blocks, blk, 0, stream>>>(Tf, Bf, g2, be2);

    // ---- layer 3: GCN(concat [Tf|Bf] 512->256) -> Af; spmm+relu -> Bf ----
    gemm_mfma_split2<0,0,1><<<g_gemm, blk, 0, stream>>>(Tf, Bf, 256, 512, W3Th, W3Tl, b3, nullptr, Af, N_NODES, 256);
    spmm_gather_bf16<1><<<row_blocks, blk, 0, stream>>>(rs3, c3, Af, Bf);

    // ---- output head: Bf @ Wout + bout -> out (fp32) ----
    gemm_mfma_split2<0,1,0><<<g_head, blk, 0, stream>>>(Bf, Bf, 256, 256, WoTh, WoTl, bout, out, nullptr, N_NODES, 100);
}

// Round 7
// 596.148 us; speedup vs baseline: 19.1085x; 1.0661x over previous
//
#include <hip/hip_runtime.h>

#define N_NODES 50000
#define E_EDGES 800000
#define NFEAT   512
#define NHID    256
#define NCLS    100
#define LN_EPS  1e-5f

#define NB     196     // row buckets of 256 rows
#define CHUNKA 6144    // edges per bin-pass block
#define CAPB   6656    // slots per bucket (exp 4096, sigma 64 -> +40 sigma)

typedef __attribute__((ext_vector_type(8))) short bf16x8;
typedef __attribute__((ext_vector_type(4))) float f32x4;

__device__ __forceinline__ ushort bf16_rne(float x) {
    unsigned u = __float_as_uint(x);
    unsigned r = u + 0x7FFFu + ((u >> 16) & 1u);
    return (ushort)(r >> 16);
}
__device__ __forceinline__ float bf16_to_f(ushort h) {
    return __uint_as_float(((unsigned)h) << 16);
}

// async global->LDS, 16 B per lane; LDS dest = wave-uniform base + lane*16
__device__ __forceinline__ void gload16(const void* g, void* l) {
    __builtin_amdgcn_global_load_lds(
        (const __attribute__((address_space(1))) unsigned int*)g,
        (__attribute__((address_space(3))) unsigned int*)l, 16, 0, 0);
}

// ---------------------------------------------------------------------------
// Weight transpose to bf16: W [K][Nc] fp32 -> WT [NP][K] bf16 (zero-padded)
// ---------------------------------------------------------------------------
__global__ __launch_bounds__(256)
void wsplit_kernel(const float* __restrict__ W, ushort* __restrict__ WT,
                   int K, int Nc, int NP)
{
    const int idx = blockIdx.x * 256 + threadIdx.x;
    if (idx >= NP * K) return;
    const int n = idx / K, k = idx - n * K;
    const float w = (n < Nc) ? W[(size_t)k * Nc + n] : 0.f;
    WT[idx] = bf16_rne(w);
}

// ---------------------------------------------------------------------------
// bf16 MFMA GEMM:  C = A[M][K] @ B[K][Nc] + bias
// A = [A1 | A2] row-major; AF32: fp32 source converted in-reg, else bf16
// staged via global_load_lds. B staged via global_load_lds (BT [NP][K] bf16).
// 128x128 tile, BK=32, 4 waves (2x2), wave tile 64x64, 16x16x32 MFMA.
// LDS linear [128][32] ushort (m97 pattern).
// ---------------------------------------------------------------------------
template<int AF32, int WF32, int WBF>
__global__ __launch_bounds__(256)
void gemm_mfma_bf16(const void* __restrict__ A1v, const void* __restrict__ A2v,
                    int K1, int K, const ushort* __restrict__ BT,
                    const float* __restrict__ bias, float* __restrict__ C,
                    ushort* __restrict__ Cbf, int M, int Nc)
{
    __shared__ __align__(16) ushort Ah[128 * 32];
    __shared__ __align__(16) ushort Bh[128 * 32];

    const int tid = threadIdx.x;
    const int bm  = blockIdx.x * 128;
    const int bn  = blockIdx.y * 128;
    const int w   = tid >> 6;
    const int l   = tid & 63;
    const int wm  = (w >> 1) * 64;
    const int wn  = (w & 1) * 64;
    const int fr  = l & 15;
    const int fq  = l >> 4;

    const int sr = tid >> 1;           // AF32 staging: row 0..127
    const int sh = (tid & 1) * 16;     // AF32 staging: ushort offset 0/16

    const int lrow = l >> 2;           // gload: row within 16-row group
    const int lch  = (l & 3) * 8;      // gload: ushort chunk 0,8,16,24

    f32x4 acc[4][4];
    #pragma unroll
    for (int i = 0; i < 4; ++i)
        #pragma unroll
        for (int j = 0; j < 4; ++j) acc[i][j] = (f32x4){0.f, 0.f, 0.f, 0.f};

    const int NS = K / 32;
    for (int s = 0; s < NS; ++s) {
        const int k0 = s * 32;
        __syncthreads();   // previous iteration's ds_reads done before overwrite

        // ---- stage B: wave w -> rows 32w..32w+31, 2 x 1024B gload ----
        {
            const ushort* g0 = &BT[(size_t)(bn + 32 * w + lrow) * K + k0 + lch];
            const ushort* g1 = &BT[(size_t)(bn + 32 * w + 16 + lrow) * K + k0 + lch];
            gload16(g0, &Bh[w * 1024]);
            gload16(g1, &Bh[w * 1024 + 512]);
        }
        // ---- stage A ----
        if (AF32) {
            const float* src; int kk, ld;
            if (k0 < K1) { src = (const float*)A1v; kk = k0;      ld = K1;     }
            else         { src = (const float*)A2v; kk = k0 - K1; ld = K - K1; }
            const int row = bm + sr;
            float xv[16];
            if (row < M) {
                const float* p = &src[(size_t)row * ld + kk + sh];
                const float4 v0 = ((const float4*)p)[0];
                const float4 v1 = ((const float4*)p)[1];
                const float4 v2 = ((const float4*)p)[2];
                const float4 v3 = ((const float4*)p)[3];
                xv[0]=v0.x; xv[1]=v0.y; xv[2]=v0.z; xv[3]=v0.w;
                xv[4]=v1.x; xv[5]=v1.y; xv[6]=v1.z; xv[7]=v1.w;
                xv[8]=v2.x; xv[9]=v2.y; xv[10]=v2.z; xv[11]=v2.w;
                xv[12]=v3.x; xv[13]=v3.y; xv[14]=v3.z; xv[15]=v3.w;
            } else {
                #pragma unroll
                for (int j = 0; j < 16; ++j) xv[j] = 0.f;
            }
            bf16x8 h0, h1;
            #pragma unroll
            for (int j = 0; j < 8; ++j) {
                h0[j] = (short)bf16_rne(xv[j]);
                h1[j] = (short)bf16_rne(xv[j + 8]);
            }
            *(bf16x8*)&Ah[sr * 32 + sh]     = h0;
            *(bf16x8*)&Ah[sr * 32 + sh + 8] = h1;
        } else {
            const ushort* src; int kk, ld;
            if (k0 < K1) { src = (const ushort*)A1v; kk = k0;      ld = K1;     }
            else         { src = (const ushort*)A2v; kk = k0 - K1; ld = K - K1; }
            // rows beyond M read workspace garbage; those C rows are discarded
            const ushort* g0 = &src[(size_t)(bm + 32 * w + lrow) * ld + kk + lch];
            const ushort* g1 = &src[(size_t)(bm + 32 * w + 16 + lrow) * ld + kk + lch];
            gload16(g0, &Ah[w * 1024]);
            gload16(g1, &Ah[w * 1024 + 512]);
        }
        __syncthreads();   // drains vmcnt (gload) + lgkm (ds_write)

        bf16x8 bf[4];
        #pragma unroll
        for (int nf = 0; nf < 4; ++nf)
            bf[nf] = *(const bf16x8*)&Bh[(wn + nf * 16 + fr) * 32 + fq * 8];
        #pragma unroll
        for (int mf = 0; mf < 4; ++mf) {
            const bf16x8 ahf = *(const bf16x8*)&Ah[(wm + mf * 16 + fr) * 32 + fq * 8];
            #pragma unroll
            for (int nf = 0; nf < 4; ++nf)
                acc[mf][nf] = __builtin_amdgcn_mfma_f32_16x16x32_bf16(ahf, bf[nf], acc[mf][nf], 0, 0, 0);
        }
    }

    #pragma unroll
    for (int mf = 0; mf < 4; ++mf) {
        #pragma unroll
        for (int r = 0; r < 4; ++r) {
            const int row = bm + wm + mf * 16 + fq * 4 + r;
            if (row >= M) continue;
            #pragma unroll
            for (int nf = 0; nf < 4; ++nf) {
                const int col = bn + wn + nf * 16 + fr;
                if (col < Nc) {
                    const float v = acc[mf][nf][r] + bias[col];
                    if (WF32) C[(size_t)row * Nc + col] = v;
                    if (WBF)  Cbf[(size_t)row * Nc + col] = bf16_rne(v);
                }
            }
        }
    }
}

// ---------------------------------------------------------------------------
// CSR build: bin -> bucket scan -> sort (writes rowstart)
// ---------------------------------------------------------------------------
__global__ __launch_bounds__(256)
void bin_kernel(const int* __restrict__ rows, const int* __restrict__ cols,
                const float* __restrict__ vals, int* __restrict__ bcur,
                int2* __restrict__ est)
{
    __shared__ int cnt[NB];
    __shared__ int scn[256];
    __shared__ int cstart[NB];
    __shared__ int ccur[NB];
    __shared__ int garr[NB];
    __shared__ __align__(16) int2 buf[CHUNKA];

    const int a  = blockIdx.y;
    const int e0 = blockIdx.x * CHUNKA;
    const int n  = min(CHUNKA, E_EDGES - e0);
    const int t  = threadIdx.x;
    const int*   rp = rows + (size_t)a * E_EDGES + e0;
    const int*   cp = cols + (size_t)a * E_EDGES + e0;
    const float* vp = vals + (size_t)a * E_EDGES + e0;

    if (t < NB) cnt[t] = 0;
    __syncthreads();
    for (int i = t; i < n; i += 256) atomicAdd(&cnt[((unsigned)rp[i]) >> 8], 1);
    __syncthreads();

    scn[t] = (t < NB) ? cnt[t] : 0;
    __syncthreads();
    for (int off = 1; off < 256; off <<= 1) {
        const int v = (t >= off) ? scn[t - off] : 0;
        __syncthreads();
        scn[t] += v;
        __syncthreads();
    }
    if (t < NB) {
        const int ex = scn[t] - cnt[t];
        cstart[t] = ex;
        ccur[t]   = ex;
        garr[t]   = atomicAdd(&bcur[a * NB + t], cnt[t]);
    }
    __syncthreads();

    for (int i = t; i < n; i += 256) {
        const unsigned r = (unsigned)rp[i];
        const int b = r >> 8;
        const int p = atomicAdd(&ccur[b], 1);
        buf[p] = make_int2((int)((r << 16) | (unsigned)cp[i]), __float_as_int(vp[i]));
    }
    __syncthreads();

    for (int i = t; i < n; i += 256) {
        const int2 en = buf[i];
        const int b = ((unsigned)en.x) >> 24;
        const int slot = garr[b] + (i - cstart[b]);
        if (slot < CAPB)
            est[((size_t)(a * NB + b)) * CAPB + slot] = en;
    }
}

__global__ __launch_bounds__(256)
void bscan_kernel(const int* __restrict__ bcur, int* __restrict__ bbase)
{
    __shared__ int s[256];
    const int a = blockIdx.x;
    const int t = threadIdx.x;
    const int v = (t < NB) ? bcur[a * NB + t] : 0;
    s[t] = v;
    __syncthreads();
    for (int off = 1; off < 256; off <<= 1) {
        const int u = (t >= off) ? s[t - off] : 0;
        __syncthreads();
        s[t] += u;
        __syncthreads();
    }
    if (t < NB) bbase[a * NB + t] = s[t] - v;
}

__global__ __launch_bounds__(256)
void sort_kernel(const int* __restrict__ bcur, const int* __restrict__ bbase,
                 const int2* __restrict__ est, int2* __restrict__ cpk,
                 int* __restrict__ rowstart)
{
    __shared__ __align__(16) int2 sbuf[CAPB];
    __shared__ __align__(16) int2 obuf[CAPB];
    __shared__ int cnt[256];
    __shared__ int scn[256];
    __shared__ int cur[256];

    const int a = blockIdx.y;
    const int b = blockIdx.x;
    const int t = threadIdx.x;
    const int nb = min(bcur[a * NB + b], CAPB);
    const size_t slots = ((size_t)(a * NB + b)) * CAPB;

    for (int i = t; i < nb; i += 256) sbuf[i] = est[slots + i];
    cnt[t] = 0;
    __syncthreads();
    for (int i = t; i < nb; i += 256)
        atomicAdd(&cnt[(((unsigned)sbuf[i].x) >> 16) & 255], 1);
    __syncthreads();

    scn[t] = cnt[t];
    __syncthreads();
    for (int off = 1; off < 256; off <<= 1) {
        const int v = (t >= off) ? scn[t - off] : 0;
        __syncthreads();
        scn[t] += v;
        __syncthreads();
    }
    const int excl = scn[t] - cnt[t];
    cur[t] = excl;

    const int bb = bbase[a * NB + b];
    const int r0 = b << 8;
    if (r0 + t < N_NODES)
        rowstart[(size_t)a * (N_NODES + 1) + r0 + t] = bb + excl;
    if (b == NB - 1 && t == 0)
        rowstart[(size_t)a * (N_NODES + 1) + N_NODES] = E_EDGES;
    __syncthreads();

    for (int i = t; i < nb; i += 256) {
        const int2 en = sbuf[i];
        const int r = (((unsigned)en.x) >> 16) & 255;
        const int p = atomicAdd(&cur[r], 1);
        obuf[p] = make_int2(en.x & 0xFFFF, en.y);
    }
    __syncthreads();

    int2* co = cpk + (size_t)a * E_EDGES + bb;
    for (int i = t; i < nb; i += 256) co[i] = obuf[i];
}

// ---------------------------------------------------------------------------
// SpMM gather over CSR, bf16 feat -> bf16 out (optional fused relu).
// ---------------------------------------------------------------------------
template<int RELU>
__global__ __launch_bounds__(256)
void spmm_gather_bf16(const int* __restrict__ rowstart, const int2* __restrict__ cpk,
                      const ushort* __restrict__ feat, ushort* __restrict__ out)
{
    const int gid  = blockIdx.x * 256 + threadIdx.x;
    const int row  = gid >> 6;
    const int lane = gid & 63;
    if (row >= N_NODES) return;

    const int s = rowstart[row];
    const int e = rowstart[row + 1];

    float4 acc0 = make_float4(0.f, 0.f, 0.f, 0.f);
    float4 acc1 = make_float4(0.f, 0.f, 0.f, 0.f);
    float4 acc2 = make_float4(0.f, 0.f, 0.f, 0.f);
    float4 acc3 = make_float4(0.f, 0.f, 0.f, 0.f);
    int j = s;
    for (; j + 3 < e; j += 4) {
        const int2 e0 = cpk[j],     e1 = cpk[j + 1];
        const int2 e2 = cpk[j + 2], e3 = cpk[j + 3];
        const ushort4 f0 = *(const ushort4*)&feat[(size_t)e0.x * NHID + lane * 4];
        const ushort4 f1 = *(const ushort4*)&feat[(size_t)e1.x * NHID + lane * 4];
        const ushort4 f2 = *(const ushort4*)&feat[(size_t)e2.x * NHID + lane * 4];
        const ushort4 f3 = *(const ushort4*)&feat[(size_t)e3.x * NHID + lane * 4];
        const float v0 = __int_as_float(e0.y), v1 = __int_as_float(e1.y);
        const float v2 = __int_as_float(e2.y), v3 = __int_as_float(e3.y);
        acc0.x += v0 * bf16_to_f(f0.x); acc0.y += v0 * bf16_to_f(f0.y);
        acc0.z += v0 * bf16_to_f(f0.z); acc0.w += v0 * bf16_to_f(f0.w);
        acc1.x += v1 * bf16_to_f(f1.x); acc1.y += v1 * bf16_to_f(f1.y);
        acc1.z += v1 * bf16_to_f(f1.z); acc1.w += v1 * bf16_to_f(f1.w);
        acc2.x += v2 * bf16_to_f(f2.x); acc2.y += v2 * bf16_to_f(f2.y);
        acc2.z += v2 * bf16_to_f(f2.z); acc2.w += v2 * bf16_to_f(f2.w);
        acc3.x += v3 * bf16_to_f(f3.x); acc3.y += v3 * bf16_to_f(f3.y);
        acc3.z += v3 * bf16_to_f(f3.z); acc3.w += v3 * bf16_to_f(f3.w);
    }
    for (; j < e; ++j) {
        const int2 ea = cpk[j];
        const float va = __int_as_float(ea.y);
        const ushort4 fa = *(const ushort4*)&feat[(size_t)ea.x * NHID + lane * 4];
        acc0.x += va * bf16_to_f(fa.x); acc0.y += va * bf16_to_f(fa.y);
        acc0.z += va * bf16_to_f(fa.z); acc0.w += va * bf16_to_f(fa.w);
    }
    float ox = acc0.x + acc1.x + acc2.x + acc3.x;
    float oy = acc0.y + acc1.y + acc2.y + acc3.y;
    float oz = acc0.z + acc1.z + acc2.z + acc3.z;
    float ow = acc0.w + acc1.w + acc2.w + acc3.w;
    if (RELU) {
        ox = fmaxf(ox, 0.f); oy = fmaxf(oy, 0.f);
        oz = fmaxf(oz, 0.f); ow = fmaxf(ow, 0.f);
    }
    ushort4 o;
    o.x = bf16_rne(ox); o.y = bf16_rne(oy);
    o.z = bf16_rne(oz); o.w = bf16_rne(ow);
    *(ushort4*)&out[(size_t)row * NHID + lane * 4] = o;
}

// ---------------------------------------------------------------------------
// In-place LayerNorm over virtual concat [A|B] (512 bf16) + affine + ReLU.
// ---------------------------------------------------------------------------
__global__ __launch_bounds__(256)
void ln_inplace_bf16(ushort* __restrict__ A, ushort* __restrict__ B,
                     const float* __restrict__ g, const float* __restrict__ be)
{
    const int gid  = blockIdx.x * 256 + threadIdx.x;
    const int row  = gid >> 6;
    const int lane = gid & 63;
    if (row >= N_NODES) return;

    ushort* src = (lane < 32) ? &A[(size_t)row * NHID + lane * 8]
                              : &B[(size_t)row * NHID + (lane - 32) * 8];
    const ushort4 a0 = ((const ushort4*)src)[0];
    const ushort4 a1 = ((const ushort4*)src)[1];
    float x[8] = {bf16_to_f(a0.x), bf16_to_f(a0.y), bf16_to_f(a0.z), bf16_to_f(a0.w),
                  bf16_to_f(a1.x), bf16_to_f(a1.y), bf16_to_f(a1.z), bf16_to_f(a1.w)};

    float s = 0.f;
    #pragma unroll
    for (int j = 0; j < 8; ++j) s += x[j];
    #pragma unroll
    for (int m = 1; m < 64; m <<= 1) s += __shfl_xor(s, m, 64);
    const float mean = s * (1.f / 512.f);

    float sq = 0.f;
    #pragma unroll
    for (int j = 0; j < 8; ++j) { const float d = x[j] - mean; sq += d * d; }
    #pragma unroll
    for (int m = 1; m < 64; m <<= 1) sq += __shfl_xor(sq, m, 64);
    const float rstd = rsqrtf(sq * (1.f / 512.f) + LN_EPS);

    const int fb = lane * 8;
    ushort4 o0, o1;
    float o[8];
    #pragma unroll
    for (int j = 0; j < 8; ++j)
        o[j] = fmaxf((x[j] - mean) * rstd * g[fb + j] + be[fb + j], 0.f);
    o0.x = bf16_rne(o[0]); o0.y = bf16_rne(o[1]); o0.z = bf16_rne(o[2]); o0.w = bf16_rne(o[3]);
    o1.x = bf16_rne(o[4]); o1.y = bf16_rne(o[5]); o1.z = bf16_rne(o[6]); o1.w = bf16_rne(o[7]);
    ((ushort4*)src)[0] = o0;
    ((ushort4*)src)[1] = o1;
}

// ---------------------------------------------------------------------------
extern "C" void kernel_launch(void* const* d_in, const int* in_sizes, int n_in,
                              void* d_out, int out_size, void* d_ws, size_t ws_size,
                              hipStream_t stream)
{
    const float* x    = (const float*)d_in[0];
    const int*   rows = (const int*)  d_in[1];
    const int*   cols = (const int*)  d_in[2];
    const float* vals = (const float*)d_in[3];
    const float* W0   = (const float*)d_in[4];
    const float* b0   = (const float*)d_in[5];
    const float* g0   = (const float*)d_in[6];
    const float* be0  = (const float*)d_in[7];
    const float* W1   = (const float*)d_in[8];
    const float* b1   = (const float*)d_in[9];
    const float* W2   = (const float*)d_in[10];
    const float* b2   = (const float*)d_in[11];
    const float* g2   = (const float*)d_in[12];
    const float* be2  = (const float*)d_in[13];
    const float* W3   = (const float*)d_in[14];
    const float* b3   = (const float*)d_in[15];
    const float* Wout = (const float*)d_in[16];
    const float* bout = (const float*)d_in[17];
    float* out = (float*)d_out;

    // ---- workspace carve ----
    char* wsb = (char*)d_ws;
    size_t off = 0;
    auto carve = [&](size_t bytes) { void* p = wsb + off; off += (bytes + 255) & ~(size_t)255; return p; };
    int*    rowstart = (int*)   carve((size_t)4 * (N_NODES + 1) * 4);
    int*    bcur     = (int*)   carve((size_t)4 * NB * 4);
    int*    bbase    = (int*)   carve((size_t)4 * NB * 4);
    int2*   cpk      = (int2*)  carve((size_t)4 * E_EDGES * 8);
    int2*   est      = (int2*)  carve((size_t)4 * NB * CAPB * 8);
    ushort* Af       = (ushort*)carve((size_t)N_NODES * NHID * 2);
    ushort* Bf       = (ushort*)carve((size_t)N_NODES * NHID * 2);
    ushort* Tf       = (ushort*)carve((size_t)N_NODES * NHID * 2);
    ushort* W0T = (ushort*)carve((size_t)256 * 512 * 2);
    ushort* W1T = (ushort*)carve((size_t)256 * 512 * 2);
    ushort* W2T = (ushort*)carve((size_t)256 * 256 * 2);
    ushort* W3T = (ushort*)carve((size_t)256 * 512 * 2);
    ushort* WoT = (ushort*)carve((size_t)128 * 256 * 2);
    carve(4096);   // guard pad after last weight (gload A-tail reads)

    const dim3 blk(256);
    const dim3 g_gemm(391, 2);
    const dim3 g_head(391, 1);
    const dim3 g_bin((E_EDGES + CHUNKA - 1) / CHUNKA, 4);   // (131, 4)
    const dim3 g_sort(NB, 4);                               // (196, 4)
    const int  row_blocks = (N_NODES * 64 + 255) / 256;     // 12500

    // ---- weight transpose (tiny) ----
    wsplit_kernel<<<(256*512 + 255)/256, blk, 0, stream>>>(W0,   W0T, 512, 256, 256);
    wsplit_kernel<<<(256*512 + 255)/256, blk, 0, stream>>>(W1,   W1T, 512, 256, 256);
    wsplit_kernel<<<(256*256 + 255)/256, blk, 0, stream>>>(W2,   W2T, 256, 256, 256);
    wsplit_kernel<<<(256*512 + 255)/256, blk, 0, stream>>>(W3,   W3T, 512, 256, 256);
    wsplit_kernel<<<(128*256 + 255)/256, blk, 0, stream>>>(Wout, WoT, 256, 100, 128);

    // ---- CSR build: bin -> bucket scan -> sort (writes rowstart) ----
    hipMemsetAsync(bcur, 0, (size_t)4 * NB * 4, stream);
    bin_kernel<<<g_bin, blk, 0, stream>>>(rows, cols, vals, bcur, est);
    bscan_kernel<<<4, blk, 0, stream>>>(bcur, bbase);
    sort_kernel<<<g_sort, blk, 0, stream>>>(bcur, bbase, est, cpk, rowstart);

    const int* rs0 = rowstart;
    const int* rs1 = rowstart + (N_NODES + 1);
    const int* rs2 = rowstart + 2 * (N_NODES + 1);
    const int* rs3 = rowstart + 3 * (N_NODES + 1);
    const int2* c0 = cpk;
    const int2* c1 = cpk + E_EDGES;
    const int2* c2 = cpk + 2 * (size_t)E_EDGES;
    const int2* c3 = cpk + 3 * (size_t)E_EDGES;

    // ---- layer 0: GraphSage(512->256): x(fp32) -> Af; agg -> Bf; LN inplace ----
    gemm_mfma_bf16<1,0,1><<<g_gemm, blk, 0, stream>>>(x, x, 512, 512, W0T, b0, nullptr, Af, N_NODES, 256);
    spmm_gather_bf16<0><<<row_blocks, blk, 0, stream>>>(rs0, c0, Af, Bf);
    ln_inplace_bf16<<<row_blocks, blk, 0, stream>>>(Af, Bf, g0, be0);

    // ---- layer 1: GCN(concat [Af|Bf] 512->256) -> Tf; spmm+relu -> Af ----
    gemm_mfma_bf16<0,0,1><<<g_gemm, blk, 0, stream>>>(Af, Bf, 256, 512, W1T, b1, nullptr, Tf, N_NODES, 256);
    spmm_gather_bf16<1><<<row_blocks, blk, 0, stream>>>(rs1, c1, Tf, Af);

    // ---- layer 2: GraphSage(256->256): Af -> Tf; agg -> Bf; LN inplace ----
    gemm_mfma_bf16<0,0,1><<<g_gemm, blk, 0, stream>>>(Af, Af, 256, 256, W2T, b2, nullptr, Tf, N_NODES, 256);
    spmm_gather_bf16<0><<<row_blocks, blk, 0, stream>>>(rs2, c2, Tf, Bf);
    ln_inplace_bf16<<<row_blocks, blk, 0, stream>>>(Tf, Bf, g2, be2);

    // ---- layer 3: GCN(concat [Tf|Bf] 512->256) -> Af; spmm+relu -> Bf ----
    gemm_mfma_bf16<0,0,1><<<g_gemm, blk, 0, stream>>>(Tf, Bf, 256, 512, W3T, b3, nullptr, Af, N_NODES, 256);
    spmm_gather_bf16<1><<<row_blocks, blk, 0, stream>>>(rs3, c3, Af, Bf);

    // ---- output head: Bf @ Wout + bout -> out (fp32) ----
    gemm_mfma_bf16<0,1,0><<<g_head, blk, 0, stream>>>(Bf, Bf, 256, 256, WoT, bout, out, nullptr, N_NODES, 100);
}

// Round 8
// 507.325 us; speedup vs baseline: 22.4540x; 1.1751x over previous
//
#include <hip/hip_runtime.h>

#define N_NODES 50000
#define E_EDGES 800000
#define NFEAT   512
#define NHID    256
#define NCLS    100
#define LN_EPS  1e-5f

#define NB     196     // row buckets of 256 rows
#define CHUNKA 6144    // edges per bin-pass block
#define CAPB   6656    // slots per bucket (exp 4096, +40 sigma)

typedef __attribute__((ext_vector_type(8))) short bf16x8;
typedef __attribute__((ext_vector_type(4))) float f32x4;

__device__ __forceinline__ ushort bf16_rne(float x) {
    unsigned u = __float_as_uint(x);
    unsigned r = u + 0x7FFFu + ((u >> 16) & 1u);
    return (ushort)(r >> 16);
}
__device__ __forceinline__ float bf16_to_f(ushort h) {
    return __uint_as_float(((unsigned)h) << 16);
}

// async global->LDS, 16 B per lane; LDS dest = wave-uniform base + lane*16
__device__ __forceinline__ void gload16(const void* g, void* l) {
    __builtin_amdgcn_global_load_lds(
        (const __attribute__((address_space(1))) unsigned int*)g,
        (__attribute__((address_space(3))) unsigned int*)l, 16, 0, 0);
}

// ---------------------------------------------------------------------------
// Weight transpose to bf16: W [K][Nc] fp32 -> WT [NP][K] bf16 (zero-padded)
// ---------------------------------------------------------------------------
__global__ __launch_bounds__(256)
void wsplit_kernel(const float* __restrict__ W, ushort* __restrict__ WT,
                   int K, int Nc, int NP)
{
    const int idx = blockIdx.x * 256 + threadIdx.x;
    if (idx >= NP * K) return;
    const int n = idx / K, k = idx - n * K;
    const float w = (n < Nc) ? W[(size_t)k * Nc + n] : 0.f;
    WT[idx] = bf16_rne(w);
}

// ---------------------------------------------------------------------------
// x fp32 -> bf16 (streaming), 8 elems/thread
// ---------------------------------------------------------------------------
__global__ __launch_bounds__(256)
void xconv_kernel(const float* __restrict__ x, ushort* __restrict__ xb, int n8)
{
    const int idx = blockIdx.x * 256 + threadIdx.x;
    if (idx >= n8) return;
    const float4 v0 = ((const float4*)x)[idx * 2];
    const float4 v1 = ((const float4*)x)[idx * 2 + 1];
    bf16x8 h;
    h[0] = (short)bf16_rne(v0.x); h[1] = (short)bf16_rne(v0.y);
    h[2] = (short)bf16_rne(v0.z); h[3] = (short)bf16_rne(v0.w);
    h[4] = (short)bf16_rne(v1.x); h[5] = (short)bf16_rne(v1.y);
    h[6] = (short)bf16_rne(v1.z); h[7] = (short)bf16_rne(v1.w);
    *(bf16x8*)&xb[idx * 8] = h;
}

// ---------------------------------------------------------------------------
// bf16 MFMA GEMM:  C = A[M][K] @ B[K][Nc] + bias
// A = [A1 | A2] bf16 row-major (source switch at K1, uniform per K-step).
// 128x128 tile, BK=32, 512 thr = 8 waves (2m x 4n), wave tile 64x32.
// Double-buffered LDS (2 x 8 KB per operand), prefetch-before-compute,
// 1 barrier / step. XOR swizzle: chunk^=(row&3), applied on gload SOURCE
// (per-lane) and ds_read (both-sides rule).
// ---------------------------------------------------------------------------
template<int WF32, int WBF>
__global__ __launch_bounds__(512)
void gemm_mfma_bf16(const ushort* __restrict__ A1, const ushort* __restrict__ A2,
                    int K1, int K, const ushort* __restrict__ BT,
                    const float* __restrict__ bias, float* __restrict__ C,
                    ushort* __restrict__ Cbf, int M, int Nc)
{
    __shared__ __align__(16) ushort Ah[2][128 * 32];
    __shared__ __align__(16) ushort Bh[2][128 * 32];

    const int tid = threadIdx.x;
    const int bm  = blockIdx.x * 128;
    const int bn  = blockIdx.y * 128;
    const int w   = tid >> 6;          // wave 0..7
    const int l   = tid & 63;
    const int wm  = (w >> 2) * 64;     // 0 / 64
    const int wn  = (w & 3) * 32;      // 0,32,64,96
    const int fr  = l & 15;
    const int fq  = l >> 4;

    // gload geometry: wave stages 16 rows (A and B each); lane l -> row 16w+(l>>2),
    // source chunk pre-swizzled so LDS slot (r,c) holds data chunk c^(r&3).
    const int gro = l >> 2;                        // 0..15
    const int gch = ((l & 3) ^ (gro & 3)) * 8;     // swizzled ushort offset
    const int ldsbase = (16 * w) * 32;             // ushorts

    f32x4 acc[4][2];
    #pragma unroll
    for (int i = 0; i < 4; ++i) {
        acc[i][0] = (f32x4){0.f, 0.f, 0.f, 0.f};
        acc[i][1] = (f32x4){0.f, 0.f, 0.f, 0.f};
    }

    const int K2 = K - K1;
    const int NS = K / 32;

    auto stage = [&](int s, int b) {
        const int k0 = s * 32;
        gload16(&BT[(size_t)(bn + 16 * w + gro) * K + k0 + gch], &Bh[b][ldsbase]);
        const ushort* asrc;
        if (k0 < K1) asrc = &A1[(size_t)(bm + 16 * w + gro) * K1 + k0 + gch];
        else         asrc = &A2[(size_t)(bm + 16 * w + gro) * K2 + (k0 - K1) + gch];
        gload16(asrc, &Ah[b][ldsbase]);
    };

    stage(0, 0);
    __syncthreads();

    int cur = 0;
    for (int s = 0; s < NS; ++s) {
        if (s + 1 < NS) stage(s + 1, cur ^ 1);   // prefetch overlaps compute

        bf16x8 bf[2];
        #pragma unroll
        for (int nf = 0; nf < 2; ++nf) {
            const int r = wn + nf * 16 + fr;
            bf[nf] = *(const bf16x8*)&Bh[cur][r * 32 + ((fq ^ (r & 3)) * 8)];
        }
        #pragma unroll
        for (int mf = 0; mf < 4; ++mf) {
            const int r = wm + mf * 16 + fr;
            const bf16x8 af = *(const bf16x8*)&Ah[cur][r * 32 + ((fq ^ (r & 3)) * 8)];
            acc[mf][0] = __builtin_amdgcn_mfma_f32_16x16x32_bf16(af, bf[0], acc[mf][0], 0, 0, 0);
            acc[mf][1] = __builtin_amdgcn_mfma_f32_16x16x32_bf16(af, bf[1], acc[mf][1], 0, 0, 0);
        }
        __syncthreads();   // drains prefetch vm + guards buffer reuse
        cur ^= 1;
    }

    // epilogue: D col = lane&15, row = (lane>>4)*4 + reg
    #pragma unroll
    for (int mf = 0; mf < 4; ++mf) {
        #pragma unroll
        for (int r = 0; r < 4; ++r) {
            const int row = bm + wm + mf * 16 + fq * 4 + r;
            if (row >= M) continue;
            #pragma unroll
            for (int nf = 0; nf < 2; ++nf) {
                const int col = bn + wn + nf * 16 + fr;
                if (col < Nc) {
                    const float v = acc[mf][nf][r] + bias[col];
                    if (WF32) C[(size_t)row * Nc + col] = v;
                    if (WBF)  Cbf[(size_t)row * Nc + col] = bf16_rne(v);
                }
            }
        }
    }
}

// ---------------------------------------------------------------------------
// CSR build: bin -> bucket scan -> sort (writes rowstart)
// ---------------------------------------------------------------------------
__global__ __launch_bounds__(256)
void bin_kernel(const int* __restrict__ rows, const int* __restrict__ cols,
                const float* __restrict__ vals, int* __restrict__ bcur,
                int2* __restrict__ est)
{
    __shared__ int cnt[NB];
    __shared__ int scn[256];
    __shared__ int cstart[NB];
    __shared__ int ccur[NB];
    __shared__ int garr[NB];
    __shared__ __align__(16) int2 buf[CHUNKA];

    const int a  = blockIdx.y;
    const int e0 = blockIdx.x * CHUNKA;
    const int n  = min(CHUNKA, E_EDGES - e0);
    const int t  = threadIdx.x;
    const int*   rp = rows + (size_t)a * E_EDGES + e0;
    const int*   cp = cols + (size_t)a * E_EDGES + e0;
    const float* vp = vals + (size_t)a * E_EDGES + e0;

    if (t < NB) cnt[t] = 0;
    __syncthreads();
    for (int i = t; i < n; i += 256) atomicAdd(&cnt[((unsigned)rp[i]) >> 8], 1);
    __syncthreads();

    scn[t] = (t < NB) ? cnt[t] : 0;
    __syncthreads();
    for (int off = 1; off < 256; off <<= 1) {
        const int v = (t >= off) ? scn[t - off] : 0;
        __syncthreads();
        scn[t] += v;
        __syncthreads();
    }
    if (t < NB) {
        const int ex = scn[t] - cnt[t];
        cstart[t] = ex;
        ccur[t]   = ex;
        garr[t]   = atomicAdd(&bcur[a * NB + t], cnt[t]);
    }
    __syncthreads();

    for (int i = t; i < n; i += 256) {
        const unsigned r = (unsigned)rp[i];
        const int b = r >> 8;
        const int p = atomicAdd(&ccur[b], 1);
        buf[p] = make_int2((int)((r << 16) | (unsigned)cp[i]), __float_as_int(vp[i]));
    }
    __syncthreads();

    for (int i = t; i < n; i += 256) {
        const int2 en = buf[i];
        const int b = ((unsigned)en.x) >> 24;
        const int slot = garr[b] + (i - cstart[b]);
        if (slot < CAPB)
            est[((size_t)(a * NB + b)) * CAPB + slot] = en;
    }
}

__global__ __launch_bounds__(256)
void bscan_kernel(const int* __restrict__ bcur, int* __restrict__ bbase)
{
    __shared__ int s[256];
    const int a = blockIdx.x;
    const int t = threadIdx.x;
    const int v = (t < NB) ? bcur[a * NB + t] : 0;
    s[t] = v;
    __syncthreads();
    for (int off = 1; off < 256; off <<= 1) {
        const int u = (t >= off) ? s[t - off] : 0;
        __syncthreads();
        s[t] += u;
        __syncthreads();
    }
    if (t < NB) bbase[a * NB + t] = s[t] - v;
}

__global__ __launch_bounds__(256)
void sort_kernel(const int* __restrict__ bcur, const int* __restrict__ bbase,
                 const int2* __restrict__ est, int2* __restrict__ cpk,
                 int* __restrict__ rowstart)
{
    __shared__ __align__(16) int2 sbuf[CAPB];
    __shared__ __align__(16) int2 obuf[CAPB];
    __shared__ int cnt[256];
    __shared__ int scn[256];
    __shared__ int cur[256];

    const int a = blockIdx.y;
    const int b = blockIdx.x;
    const int t = threadIdx.x;
    const int nb = min(bcur[a * NB + b], CAPB);
    const size_t slots = ((size_t)(a * NB + b)) * CAPB;

    for (int i = t; i < nb; i += 256) sbuf[i] = est[slots + i];
    cnt[t] = 0;
    __syncthreads();
    for (int i = t; i < nb; i += 256)
        atomicAdd(&cnt[(((unsigned)sbuf[i].x) >> 16) & 255], 1);
    __syncthreads();

    scn[t] = cnt[t];
    __syncthreads();
    for (int off = 1; off < 256; off <<= 1) {
        const int v = (t >= off) ? scn[t - off] : 0;
        __syncthreads();
        scn[t] += v;
        __syncthreads();
    }
    const int excl = scn[t] - cnt[t];
    cur[t] = excl;

    const int bb = bbase[a * NB + b];
    const int r0 = b << 8;
    if (r0 + t < N_NODES)
        rowstart[(size_t)a * (N_NODES + 1) + r0 + t] = bb + excl;
    if (b == NB - 1 && t == 0)
        rowstart[(size_t)a * (N_NODES + 1) + N_NODES] = E_EDGES;
    __syncthreads();

    for (int i = t; i < nb; i += 256) {
        const int2 en = sbuf[i];
        const int r = (((unsigned)en.x) >> 16) & 255;
        const int p = atomicAdd(&cur[r], 1);
        obuf[p] = make_int2(en.x & 0xFFFF, en.y);
    }
    __syncthreads();

    int2* co = cpk + (size_t)a * E_EDGES + bb;
    for (int i = t; i < nb; i += 256) co[i] = obuf[i];
}

// ---------------------------------------------------------------------------
// SpMM gather over CSR with 16-edge cooperative broadcast (MLP=16).
// LNFUSE=0: out0 = relu(agg) bf16.
// LNFUSE=1: LayerNorm over concat [feat[row] | agg] (512) + affine + relu;
//           out0 = LN'd feat half, out1 = LN'd agg half.
// ---------------------------------------------------------------------------
template<int LNFUSE>
__global__ __launch_bounds__(256)
void spmm_kernel(const int* __restrict__ rowstart, const int2* __restrict__ cpk,
                 const ushort* __restrict__ feat, ushort* __restrict__ out0,
                 ushort* __restrict__ out1, const float* __restrict__ g,
                 const float* __restrict__ be)
{
    const int gid  = blockIdx.x * 256 + threadIdx.x;
    const int row  = gid >> 6;
    const int lane = gid & 63;
    if (row >= N_NODES) return;

    const int s = rowstart[row];
    const int e = rowstart[row + 1];

    float ax = 0.f, ay = 0.f, az = 0.f, aw = 0.f;
    for (int j = s; j < e; j += 16) {
        const int idx = j + (lane & 15);
        int2 ev = make_int2(0, 0);
        if (idx < e) ev = cpk[idx];
        #pragma unroll
        for (int q = 0; q < 16; ++q) {
            const int   c = __shfl(ev.x, q, 16);
            const float v = __int_as_float(__shfl(ev.y, q, 16));
            const ushort4 f = *(const ushort4*)&feat[(size_t)c * NHID + lane * 4];
            ax += v * bf16_to_f(f.x); ay += v * bf16_to_f(f.y);
            az += v * bf16_to_f(f.z); aw += v * bf16_to_f(f.w);
        }
    }

    if (LNFUSE) {
        const ushort4 fx = *(const ushort4*)&feat[(size_t)row * NHID + lane * 4];
        float xf[4] = {bf16_to_f(fx.x), bf16_to_f(fx.y), bf16_to_f(fx.z), bf16_to_f(fx.w)};

        float sum = xf[0] + xf[1] + xf[2] + xf[3] + ax + ay + az + aw;
        #pragma unroll
        for (int m = 1; m < 64; m <<= 1) sum += __shfl_xor(sum, m, 64);
        const float mean = sum * (1.f / 512.f);

        float sq = 0.f;
        #pragma unroll
        for (int jj = 0; jj < 4; ++jj) { const float d = xf[jj] - mean; sq += d * d; }
        { float d; d = ax - mean; sq += d * d; d = ay - mean; sq += d * d;
          d = az - mean; sq += d * d; d = aw - mean; sq += d * d; }
        #pragma unroll
        for (int m = 1; m < 64; m <<= 1) sq += __shfl_xor(sq, m, 64);
        const float rstd = rsqrtf(sq * (1.f / 512.f) + LN_EPS);

        const int col = lane * 4;
        const float av[4] = {ax, ay, az, aw};
        ushort4 o0, o1;
        float t0[4], t1[4];
        #pragma unroll
        for (int jj = 0; jj < 4; ++jj) {
            t0[jj] = fmaxf((xf[jj] - mean) * rstd * g[col + jj] + be[col + jj], 0.f);
            t1[jj] = fmaxf((av[jj] - mean) * rstd * g[256 + col + jj] + be[256 + col + jj], 0.f);
        }
        o0.x = bf16_rne(t0[0]); o0.y = bf16_rne(t0[1]); o0.z = bf16_rne(t0[2]); o0.w = bf16_rne(t0[3]);
        o1.x = bf16_rne(t1[0]); o1.y = bf16_rne(t1[1]); o1.z = bf16_rne(t1[2]); o1.w = bf16_rne(t1[3]);
        *(ushort4*)&out0[(size_t)row * NHID + col] = o0;
        *(ushort4*)&out1[(size_t)row * NHID + col] = o1;
    } else {
        ushort4 o;
        o.x = bf16_rne(fmaxf(ax, 0.f)); o.y = bf16_rne(fmaxf(ay, 0.f));
        o.z = bf16_rne(fmaxf(az, 0.f)); o.w = bf16_rne(fmaxf(aw, 0.f));
        *(ushort4*)&out0[(size_t)row * NHID + lane * 4] = o;
    }
}

// ---------------------------------------------------------------------------
extern "C" void kernel_launch(void* const* d_in, const int* in_sizes, int n_in,
                              void* d_out, int out_size, void* d_ws, size_t ws_size,
                              hipStream_t stream)
{
    const float* x    = (const float*)d_in[0];
    const int*   rows = (const int*)  d_in[1];
    const int*   cols = (const int*)  d_in[2];
    const float* vals = (const float*)d_in[3];
    const float* W0   = (const float*)d_in[4];
    const float* b0   = (const float*)d_in[5];
    const float* g0   = (const float*)d_in[6];
    const float* be0  = (const float*)d_in[7];
    const float* W1   = (const float*)d_in[8];
    const float* b1   = (const float*)d_in[9];
    const float* W2   = (const float*)d_in[10];
    const float* b2   = (const float*)d_in[11];
    const float* g2   = (const float*)d_in[12];
    const float* be2  = (const float*)d_in[13];
    const float* W3   = (const float*)d_in[14];
    const float* b3   = (const float*)d_in[15];
    const float* Wout = (const float*)d_in[16];
    const float* bout = (const float*)d_in[17];
    float* out = (float*)d_out;

    // ---- workspace carve ----
    char* wsb = (char*)d_ws;
    size_t off = 0;
    auto carve = [&](size_t bytes) { void* p = wsb + off; off += (bytes + 255) & ~(size_t)255; return p; };
    int*    rowstart = (int*)   carve((size_t)4 * (N_NODES + 1) * 4);
    int*    bcur     = (int*)   carve((size_t)4 * NB * 4);
    int*    bbase    = (int*)   carve((size_t)4 * NB * 4);
    int2*   cpk      = (int2*)  carve((size_t)4 * E_EDGES * 8);
    int2*   est      = (int2*)  carve((size_t)4 * NB * CAPB * 8);
    ushort* Xb       = (ushort*)carve((size_t)N_NODES * NFEAT * 2);   // bf16 x
    ushort* F        = (ushort*)carve((size_t)N_NODES * NHID * 2);    // feat
    ushort* P        = (ushort*)carve((size_t)N_NODES * NHID * 2);    // LN feat half
    ushort* Q        = (ushort*)carve((size_t)N_NODES * NHID * 2);    // LN agg half
    ushort* G        = (ushort*)carve((size_t)N_NODES * NHID * 2);    // GCN lin out
    ushort* H        = (ushort*)carve((size_t)N_NODES * NHID * 2);    // GCN relu(agg)
    ushort* W0T = (ushort*)carve((size_t)256 * 512 * 2);
    ushort* W1T = (ushort*)carve((size_t)256 * 512 * 2);
    ushort* W2T = (ushort*)carve((size_t)256 * 256 * 2);
    ushort* W3T = (ushort*)carve((size_t)256 * 512 * 2);
    ushort* WoT = (ushort*)carve((size_t)128 * 256 * 2);
    carve(131072);   // guard pad (gload A-tail overreads, <= 48 rows * 1 KB)

    const dim3 blk(256);
    const dim3 blkg(512);
    const dim3 g_gemm(391, 2);
    const dim3 g_head(391, 1);
    const dim3 g_bin((E_EDGES + CHUNKA - 1) / CHUNKA, 4);   // (131, 4)
    const dim3 g_sort(NB, 4);                               // (196, 4)
    const int  row_blocks = (N_NODES * 64 + 255) / 256;     // 12500

    // ---- weight transpose + x convert (small streaming) ----
    wsplit_kernel<<<(256*512 + 255)/256, blk, 0, stream>>>(W0,   W0T, 512, 256, 256);
    wsplit_kernel<<<(256*512 + 255)/256, blk, 0, stream>>>(W1,   W1T, 512, 256, 256);
    wsplit_kernel<<<(256*256 + 255)/256, blk, 0, stream>>>(W2,   W2T, 256, 256, 256);
    wsplit_kernel<<<(256*512 + 255)/256, blk, 0, stream>>>(W3,   W3T, 512, 256, 256);
    wsplit_kernel<<<(128*256 + 255)/256, blk, 0, stream>>>(Wout, WoT, 256, 100, 128);
    xconv_kernel<<<(N_NODES * NFEAT / 8 + 255)/256, blk, 0, stream>>>(x, Xb, N_NODES * NFEAT / 8);

    // ---- CSR build: bin -> bucket scan -> sort (writes rowstart) ----
    hipMemsetAsync(bcur, 0, (size_t)4 * NB * 4, stream);
    bin_kernel<<<g_bin, blk, 0, stream>>>(rows, cols, vals, bcur, est);
    bscan_kernel<<<4, blk, 0, stream>>>(bcur, bbase);
    sort_kernel<<<g_sort, blk, 0, stream>>>(bcur, bbase, est, cpk, rowstart);

    const int* rs0 = rowstart;
    const int* rs1 = rowstart + (N_NODES + 1);
    const int* rs2 = rowstart + 2 * (N_NODES + 1);
    const int* rs3 = rowstart + 3 * (N_NODES + 1);
    const int2* c0 = cpk;
    const int2* c1 = cpk + E_EDGES;
    const int2* c2 = cpk + 2 * (size_t)E_EDGES;
    const int2* c3 = cpk + 3 * (size_t)E_EDGES;

    // ---- layer 0: GraphSage(512->256): Xb -> F; spmm+LN -> P,Q ----
    gemm_mfma_bf16<0,1><<<g_gemm, blkg, 0, stream>>>(Xb, Xb, 512, 512, W0T, b0, nullptr, F, N_NODES, 256);
    spmm_kernel<1><<<row_blocks, blk, 0, stream>>>(rs0, c0, F, P, Q, g0, be0);

    // ---- layer 1: GCN(concat [P|Q] 512->256) -> G; spmm+relu -> H ----
    gemm_mfma_bf16<0,1><<<g_gemm, blkg, 0, stream>>>(P, Q, 256, 512, W1T, b1, nullptr, G, N_NODES, 256);
    spmm_kernel<0><<<row_blocks, blk, 0, stream>>>(rs1, c1, G, H, nullptr, nullptr, nullptr);

    // ---- layer 2: GraphSage(256->256): H -> F; spmm+LN -> P,Q ----
    gemm_mfma_bf16<0,1><<<g_gemm, blkg, 0, stream>>>(H, H, 256, 256, W2T, b2, nullptr, F, N_NODES, 256);
    spmm_kernel<1><<<row_blocks, blk, 0, stream>>>(rs2, c2, F, P, Q, g2, be2);

    // ---- layer 3: GCN(concat [P|Q] 512->256) -> G; spmm+relu -> H ----
    gemm_mfma_bf16<0,1><<<g_gemm, blkg, 0, stream>>>(P, Q, 256, 512, W3T, b3, nullptr, G, N_NODES, 256);
    spmm_kernel<0><<<row_blocks, blk, 0, stream>>>(rs3, c3, G, H, nullptr, nullptr, nullptr);

    // ---- output head: H @ WoT + bout -> out (fp32) ----
    gemm_mfma_bf16<1,0><<<g_head, blkg, 0, stream>>>(H, H, 256, 256, WoT, bout, out, nullptr, N_NODES, 100);
}